// Round 1
// baseline (1607.624 us; speedup 1.0000x reference)
//
#include <hip/hip_runtime.h>
#include <hip/hip_bf16.h>

// ---------------- problem constants ----------------
#define NU 40000
#define EU 640000
#define BB 64
#define TT 16
#define NW 30
#define NTNODES 30720       // B*T*NW
#define NTE 61440           // tweet edges
#define NSEG_T 1024         // B*T

// ---------------- small utility kernels ----------------
__global__ void k_fill1(float* __restrict__ p, int n) {
    int i = blockIdx.x * blockDim.x + threadIdx.x;
    if (i < n) p[i] = 1.0f;
}

__global__ void k_count(const int* __restrict__ dst, float* __restrict__ deg, int E) {
    int i = blockIdx.x * blockDim.x + threadIdx.x;
    if (i < E) atomicAdd(&deg[dst[i]], 1.0f);
}

__global__ void k_rsqrt(float* __restrict__ p, int n) {
    int i = blockIdx.x * blockDim.x + threadIdx.x;
    if (i < n) p[i] = rsqrtf(p[i]);
}

// out[v,c] = dinv[v]^2 * y[v,c]   (self-loop init, float4)
__global__ void k_selfinit(const float* __restrict__ y, const float* __restrict__ dinv,
                           float* __restrict__ out, long total, int C) {
    long i = ((long)blockIdx.x * blockDim.x + threadIdx.x) * 4;
    if (i >= total) return;
    float di = dinv[i / C];
    float s = di * di;
    float4 v = *(const float4*)(y + i);
    v.x *= s; v.y *= s; v.z *= s; v.w *= s;
    *(float4*)(out + i) = v;
}

// wave-per-edge scatter: out[d,:] += dinv[s]*dinv[d]*y[s,:]
__global__ __launch_bounds__(256) void k_scatter(const int* __restrict__ src,
                                                 const int* __restrict__ dst,
                                                 const float* __restrict__ dinv,
                                                 const float* __restrict__ y,
                                                 float* __restrict__ out, int E, int C) {
    int e = blockIdx.x * (blockDim.x >> 6) + (threadIdx.x >> 6);
    if (e >= E) return;
    int lane = threadIdx.x & 63;
    int s = src[e], d = dst[e];
    float coef = dinv[s] * dinv[d];
    const float* yr = y + (size_t)s * C;
    float* orow = out + (size_t)d * C;
    for (int c = lane; c < C; c += 64)
        atomicAdd(&orow[c], coef * yr[c]);
}

// out = relu(out + bias[c])   (float4)
__global__ void k_biasrelu(float* __restrict__ out, const float* __restrict__ b,
                           long total, int C) {
    long i = ((long)blockIdx.x * blockDim.x + threadIdx.x) * 4;
    if (i >= total) return;
    int c = (int)(i % C);
    float4 v = *(float4*)(out + i);
    v.x = fmaxf(v.x + b[c + 0], 0.f);
    v.y = fmaxf(v.y + b[c + 1], 0.f);
    v.z = fmaxf(v.z + b[c + 2], 0.f);
    v.w = fmaxf(v.w + b[c + 3], 0.f);
    *(float4*)(out + i) = v;
}

// ---------------- tiled fp32 GEMM: C = A[M,K] @ W[K,N] (+bias)(+relu) ----------------
#define GBM 64
#define GBN 64
#define GBK 16
// flags: bit0 = add bias, bit1 = relu
__global__ __launch_bounds__(256) void k_gemm(const float* __restrict__ A,
                                              const float* __restrict__ W,
                                              const float* __restrict__ bias,
                                              float* __restrict__ C,
                                              int M, int K, int N, int flags) {
    __shared__ float As[GBK][GBM];
    __shared__ float Ws[GBK][GBN];
    int tid = threadIdx.x;
    int bm = blockIdx.x, bn = blockIdx.y;
    int tx = tid & 15, ty = tid >> 4;
    float acc[4][4] = {};

    int arow = tid >> 2;          // 0..63
    int akq  = (tid & 3) * 4;     // k offset within tile
    int wrow = tid >> 4;          // 0..15
    int wcol = (tid & 15) * 4;

    const float* Aptr = A + (size_t)(bm * GBM + arow) * K + akq;
    const float* Wptr = W + (size_t)wrow * N + (size_t)bn * GBN + wcol;

    for (int k0 = 0; k0 < K; k0 += GBK) {
        float4 av = *(const float4*)(Aptr + k0);
        float4 wv = *(const float4*)(Wptr + (size_t)k0 * N);
        As[akq + 0][arow] = av.x;
        As[akq + 1][arow] = av.y;
        As[akq + 2][arow] = av.z;
        As[akq + 3][arow] = av.w;
        *(float4*)&Ws[wrow][wcol] = wv;
        __syncthreads();
#pragma unroll
        for (int kk = 0; kk < GBK; ++kk) {
            float a0 = As[kk][ty * 4 + 0], a1 = As[kk][ty * 4 + 1];
            float a2 = As[kk][ty * 4 + 2], a3 = As[kk][ty * 4 + 3];
            float w0 = Ws[kk][tx * 4 + 0], w1 = Ws[kk][tx * 4 + 1];
            float w2 = Ws[kk][tx * 4 + 2], w3 = Ws[kk][tx * 4 + 3];
            acc[0][0] += a0 * w0; acc[0][1] += a0 * w1; acc[0][2] += a0 * w2; acc[0][3] += a0 * w3;
            acc[1][0] += a1 * w0; acc[1][1] += a1 * w1; acc[1][2] += a1 * w2; acc[1][3] += a1 * w3;
            acc[2][0] += a2 * w0; acc[2][1] += a2 * w1; acc[2][2] += a2 * w2; acc[2][3] += a2 * w3;
            acc[3][0] += a3 * w0; acc[3][1] += a3 * w1; acc[3][2] += a3 * w2; acc[3][3] += a3 * w3;
        }
        __syncthreads();
    }

#pragma unroll
    for (int i = 0; i < 4; ++i) {
        int row = bm * GBM + ty * 4 + i;
        int col = bn * GBN + tx * 4;
        float4 v = make_float4(acc[i][0], acc[i][1], acc[i][2], acc[i][3]);
        if (flags & 1) {
            v.x += bias[col + 0]; v.y += bias[col + 1];
            v.z += bias[col + 2]; v.w += bias[col + 3];
        }
        if (flags & 2) {
            v.x = fmaxf(v.x, 0.f); v.y = fmaxf(v.y, 0.f);
            v.z = fmaxf(v.z, 0.f); v.w = fmaxf(v.w, 0.f);
        }
        *(float4*)(C + (size_t)row * N + col) = v;
    }
}

// ---------------- attention pooling (contiguous equal segments, C=128) ----------------
__global__ __launch_bounds__(128) void k_attpool(const float* __restrict__ x,
                                                 const float* __restrict__ gate,
                                                 float* __restrict__ out, int S) {
    const int C = 128;
    int seg = blockIdx.x;
    int c = threadIdx.x;
    size_t base = (size_t)seg * S * C + c;
    float m = -1e30f;
    for (int n = 0; n < S; ++n) m = fmaxf(m, gate[base + (size_t)n * C]);
    float se = 0.f, acc = 0.f;
    for (int n = 0; n < S; ++n) {
        float g = gate[base + (size_t)n * C];
        float e = expf(g - m);
        se += e;
        acc += e * x[base + (size_t)n * C];
    }
    out[(size_t)seg * C + c] = acc / (se + 1e-16f);
}

// ---------------- GRU over T=16 steps, hidden=128, one block per batch ----------------
__global__ __launch_bounds__(128) void k_gru(const float* __restrict__ seq,
                                             const float* __restrict__ Wih,
                                             const float* __restrict__ bih,
                                             const float* __restrict__ Whh,
                                             const float* __restrict__ bhh,
                                             float* __restrict__ hT) {
    __shared__ float xs[128], hs[128];
    int b = blockIdx.x, j = threadIdx.x;
    hs[j] = 0.f;
    const float* wr = Wih + (size_t)j * 128;
    const float* wz = Wih + (size_t)(128 + j) * 128;
    const float* wn = Wih + (size_t)(256 + j) * 128;
    const float* ur = Whh + (size_t)j * 128;
    const float* uz = Whh + (size_t)(128 + j) * 128;
    const float* un = Whh + (size_t)(256 + j) * 128;
    float br = bih[j], bz = bih[128 + j], bn = bih[256 + j];
    float cr = bhh[j], cz = bhh[128 + j], cn = bhh[256 + j];
    for (int t = 0; t < TT; ++t) {
        xs[j] = seq[((size_t)b * TT + t) * 128 + j];
        __syncthreads();
        float ir = br, iz = bz, in = bn, hr = cr, hz = cz, hn = cn;
        for (int k = 0; k < 128; ++k) {
            float xk = xs[k], hk = hs[k];
            ir += xk * wr[k]; iz += xk * wz[k]; in += xk * wn[k];
            hr += hk * ur[k]; hz += hk * uz[k]; hn += hk * un[k];
        }
        float r = 1.f / (1.f + expf(-(ir + hr)));
        float z = 1.f / (1.f + expf(-(iz + hz)));
        float n = tanhf(in + r * hn);
        float hnew = (1.f - z) * n + z * hs[j];
        __syncthreads();
        hs[j] = hnew;
        __syncthreads();
    }
    hT[(size_t)b * 128 + j] = hs[j];
}

// ---------------- head MLP: [32|128|128] -> 256 relu -> 64 relu -> 1 sigmoid ----------------
__global__ __launch_bounds__(256) void k_head(const float* __restrict__ uf,
                                              const float* __restrict__ up,
                                              const float* __restrict__ th,
                                              const float* __restrict__ Wd0, const float* __restrict__ bd0,
                                              const float* __restrict__ Wd1, const float* __restrict__ bd1,
                                              const float* __restrict__ Wp, const float* __restrict__ bp,
                                              float* __restrict__ out) {
    __shared__ float in0[288], l1[256], l2[64];
    int b = blockIdx.x, t = threadIdx.x;
    if (t < 32) in0[t] = uf[b * 32 + t];
    else if (t < 160) in0[t] = up[b * 128 + (t - 32)];
    // remaining 128 entries loaded by first 128 threads too (loop form):
    if (t < 128) in0[160 + t] = th[b * 128 + t];
    __syncthreads();
    float acc = bd0[t];
    for (int k = 0; k < 288; ++k) acc += in0[k] * Wd0[k * 256 + t];
    l1[t] = fmaxf(acc, 0.f);
    __syncthreads();
    if (t < 64) {
        float a2 = bd1[t];
        for (int k = 0; k < 256; ++k) a2 += l1[k] * Wd1[k * 64 + t];
        l2[t] = fmaxf(a2, 0.f);
    }
    __syncthreads();
    if (t < 64) {
        float p = l2[t] * Wp[t];
        for (int off = 32; off; off >>= 1) p += __shfl_down(p, off, 64);
        if (t == 0) out[b] = 1.f / (1.f + expf(-(p + bp[0])));
    }
}

// ---------------- launch ----------------
extern "C" void kernel_launch(void* const* d_in, const int* in_sizes, int n_in,
                              void* d_out, int out_size, void* d_ws, size_t ws_size,
                              hipStream_t stream) {
    const float* user_x     = (const float*)d_in[0];
    const float* user_feats = (const float*)d_in[1];
    const float* tweet_x    = (const float*)d_in[2];
    const float* Wu0 = (const float*)d_in[3];  const float* bu0 = (const float*)d_in[4];
    const float* Wu1 = (const float*)d_in[5];  const float* bu1 = (const float*)d_in[6];
    const float* Wgu1 = (const float*)d_in[7]; const float* bgu1 = (const float*)d_in[8];
    const float* Wgu2 = (const float*)d_in[9]; const float* bgu2 = (const float*)d_in[10];
    const float* Wt0 = (const float*)d_in[11]; const float* bt0 = (const float*)d_in[12];
    const float* Wt1 = (const float*)d_in[13]; const float* bt1 = (const float*)d_in[14];
    const float* Wgt1 = (const float*)d_in[15]; const float* bgt1 = (const float*)d_in[16];
    const float* Wgt2 = (const float*)d_in[17]; const float* bgt2 = (const float*)d_in[18];
    const float* W_ih = (const float*)d_in[19]; const float* b_ih = (const float*)d_in[20];
    const float* W_hh = (const float*)d_in[21]; const float* b_hh = (const float*)d_in[22];
    const float* Wd0 = (const float*)d_in[23]; const float* bd0 = (const float*)d_in[24];
    const float* Wd1 = (const float*)d_in[25]; const float* bd1 = (const float*)d_in[26];
    const float* Wp  = (const float*)d_in[27]; const float* bp  = (const float*)d_in[28];
    const int* ue = (const int*)d_in[29];           // [2, EU]
    const int* te = (const int*)d_in[30];           // [2, NTE]
    const int* ue_src = ue, *ue_dst = ue + EU;
    const int* te_src = te, *te_dst = te + NTE;

    float* ws = (float*)d_ws;
    // region0 (shared between branches): tweet needs 2*NT*256 = 15,728,640 floats
    // user bufs (3 * NU*128 = 15,360,000 floats) alias into the same region.
    float* region0 = ws;
    const size_t R0 = (size_t)NTNODES * 256 * 2;
    float* bufA = region0;
    float* bufB = region0 + (size_t)NU * 128;
    float* bufC = region0 + (size_t)NU * 128 * 2;
    float* tA = region0;
    float* tB = region0 + (size_t)NTNODES * 256;
    size_t o = R0;
    float* dinv_u = ws + o;     o += NU;
    float* dinv_t = ws + o;     o += NTNODES;
    float* user_pool = ws + o;  o += (size_t)BB * 128;
    float* tweet_pool = ws + o; o += (size_t)NSEG_T * 128;
    float* tweet_h = ws + o;    o += (size_t)BB * 128;
    float* out = (float*)d_out;

    // ---- degrees ----
    hipLaunchKernelGGL(k_fill1, dim3((NU + 255) / 256), dim3(256), 0, stream, dinv_u, NU);
    hipLaunchKernelGGL(k_count, dim3((EU + 255) / 256), dim3(256), 0, stream, ue_dst, dinv_u, EU);
    hipLaunchKernelGGL(k_rsqrt, dim3((NU + 255) / 256), dim3(256), 0, stream, dinv_u, NU);
    hipLaunchKernelGGL(k_fill1, dim3((NTNODES + 255) / 256), dim3(256), 0, stream, dinv_t, NTNODES);
    hipLaunchKernelGGL(k_count, dim3((NTE + 255) / 256), dim3(256), 0, stream, te_dst, dinv_t, NTE);
    hipLaunchKernelGGL(k_rsqrt, dim3((NTNODES + 255) / 256), dim3(256), 0, stream, dinv_t, NTNODES);

    const long U128 = (long)NU * 128;
    const long T256 = (long)NTNODES * 256;
    const long T128 = (long)NTNODES * 128;
    dim3 b256(256);
    dim3 gU128((U128 / 4 + 255) / 256), gT256((T256 / 4 + 255) / 256), gT128((T128 / 4 + 255) / 256);

    // ---- user branch ----
    // conv1
    hipLaunchKernelGGL(k_gemm, dim3(NU / GBM, 128 / GBN), b256, 0, stream,
                       user_x, Wu0, (const float*)nullptr, bufA, NU, 128, 128, 0);
    hipLaunchKernelGGL(k_selfinit, gU128, b256, 0, stream, bufA, dinv_u, bufB, U128, 128);
    hipLaunchKernelGGL(k_scatter, dim3((EU + 3) / 4), b256, 0, stream,
                       ue_src, ue_dst, dinv_u, bufA, bufB, EU, 128);
    hipLaunchKernelGGL(k_biasrelu, gU128, b256, 0, stream, bufB, bu0, U128, 128);
    // conv2
    hipLaunchKernelGGL(k_gemm, dim3(NU / GBM, 128 / GBN), b256, 0, stream,
                       bufB, Wu1, (const float*)nullptr, bufA, NU, 128, 128, 0);
    hipLaunchKernelGGL(k_selfinit, gU128, b256, 0, stream, bufA, dinv_u, bufC, U128, 128);
    hipLaunchKernelGGL(k_scatter, dim3((EU + 3) / 4), b256, 0, stream,
                       ue_src, ue_dst, dinv_u, bufA, bufC, EU, 128);
    hipLaunchKernelGGL(k_biasrelu, gU128, b256, 0, stream, bufC, bu1, U128, 128);
    // gate + pool
    hipLaunchKernelGGL(k_gemm, dim3(NU / GBM, 128 / GBN), b256, 0, stream,
                       bufC, Wgu1, bgu1, bufA, NU, 128, 128, 1);
    hipLaunchKernelGGL(k_gemm, dim3(NU / GBM, 128 / GBN), b256, 0, stream,
                       bufA, Wgu2, bgu2, bufB, NU, 128, 128, 1);
    hipLaunchKernelGGL(k_attpool, dim3(BB), dim3(128), 0, stream, bufC, bufB, user_pool, NU / BB);

    // ---- tweet branch ----
    // conv1 (768 -> 256)
    hipLaunchKernelGGL(k_gemm, dim3(NTNODES / GBM, 256 / GBN), b256, 0, stream,
                       tweet_x, Wt0, (const float*)nullptr, tA, NTNODES, 768, 256, 0);
    hipLaunchKernelGGL(k_selfinit, gT256, b256, 0, stream, tA, dinv_t, tB, T256, 256);
    hipLaunchKernelGGL(k_scatter, dim3((NTE + 3) / 4), b256, 0, stream,
                       te_src, te_dst, dinv_t, tA, tB, NTE, 256);
    hipLaunchKernelGGL(k_biasrelu, gT256, b256, 0, stream, tB, bt0, T256, 256);
    // conv2 (256 -> 128)
    hipLaunchKernelGGL(k_gemm, dim3(NTNODES / GBM, 128 / GBN), b256, 0, stream,
                       tB, Wt1, (const float*)nullptr, tA, NTNODES, 256, 128, 0);
    hipLaunchKernelGGL(k_selfinit, gT128, b256, 0, stream, tA, dinv_t, tB, T128, 128);
    hipLaunchKernelGGL(k_scatter, dim3((NTE + 3) / 4), b256, 0, stream,
                       te_src, te_dst, dinv_t, tA, tB, NTE, 128);
    hipLaunchKernelGGL(k_biasrelu, gT128, b256, 0, stream, tB, bt1, T128, 128);
    // gate + pool
    hipLaunchKernelGGL(k_gemm, dim3(NTNODES / GBM, 128 / GBN), b256, 0, stream,
                       tB, Wgt1, bgt1, tA, NTNODES, 128, 128, 1);
    hipLaunchKernelGGL(k_gemm, dim3(NTNODES / GBM, 128 / GBN), b256, 0, stream,
                       tA, Wgt2, bgt2, tA + T128, NTNODES, 128, 128, 1);
    hipLaunchKernelGGL(k_attpool, dim3(NSEG_T), dim3(128), 0, stream, tB, tA + T128, tweet_pool, NW);

    // ---- GRU ----
    hipLaunchKernelGGL(k_gru, dim3(BB), dim3(128), 0, stream,
                       tweet_pool, W_ih, b_ih, W_hh, b_hh, tweet_h);

    // ---- head ----
    hipLaunchKernelGGL(k_head, dim3(BB), b256, 0, stream,
                       user_feats, user_pool, tweet_h,
                       Wd0, bd0, Wd1, bd1, Wp, bp, out);
}

// Round 2
// 1332.569 us; speedup vs baseline: 1.2064x; 1.2064x over previous
//
#include <hip/hip_runtime.h>
#include <hip/hip_bf16.h>

// ---------------- problem constants ----------------
#define NU 40000
#define EU 640000
#define BB 64
#define TT 16
#define NW 30
#define NTNODES 30720       // B*T*NW
#define NTE 61440           // tweet edges
#define NSEG_T 1024         // B*T
#define NCHUNK 16           // chunks per user segment for att-pool

// ---------------- degree kernels (user+tweet fused; dinv_t = dinv_u + NU) ----------------
__global__ void k_fill1(float* __restrict__ p, int n) {
    int i = blockIdx.x * blockDim.x + threadIdx.x;
    if (i < n) p[i] = 1.0f;
}

__global__ void k_count2(const int* __restrict__ ue_dst, const int* __restrict__ te_dst,
                         float* __restrict__ deg_u, float* __restrict__ deg_t) {
    int i = blockIdx.x * blockDim.x + threadIdx.x;
    if (i < EU) atomicAdd(&deg_u[ue_dst[i]], 1.0f);
    else if (i < EU + NTE) atomicAdd(&deg_t[te_dst[i - EU]], 1.0f);
}

__global__ void k_rsqrt(float* __restrict__ p, int n) {
    int i = blockIdx.x * blockDim.x + threadIdx.x;
    if (i < n) p[i] = rsqrtf(p[i]);
}

// wave-per-edge scatter: out[d,:] += dinv[s]*dinv[d]*y[s,:]
__global__ __launch_bounds__(256) void k_scatter(const int* __restrict__ src,
                                                 const int* __restrict__ dst,
                                                 const float* __restrict__ dinv,
                                                 const float* __restrict__ y,
                                                 float* __restrict__ out, int E, int C) {
    int e = blockIdx.x * (blockDim.x >> 6) + (threadIdx.x >> 6);
    if (e >= E) return;
    int lane = threadIdx.x & 63;
    int s = src[e], d = dst[e];
    float coef = dinv[s] * dinv[d];
    const float* yr = y + (size_t)s * C;
    float* orow = out + (size_t)d * C;
    for (int c = lane; c < C; c += 64)
        atomicAdd(&orow[c], coef * yr[c]);
}

// out = relu(out + bias[c])   (float4)
__global__ void k_biasrelu(float* __restrict__ out, const float* __restrict__ b,
                           long total, int C) {
    long i = ((long)blockIdx.x * blockDim.x + threadIdx.x) * 4;
    if (i >= total) return;
    int c = (int)(i % C);
    float4 v = *(float4*)(out + i);
    v.x = fmaxf(v.x + b[c + 0], 0.f);
    v.y = fmaxf(v.y + b[c + 1], 0.f);
    v.z = fmaxf(v.z + b[c + 2], 0.f);
    v.w = fmaxf(v.w + b[c + 3], 0.f);
    *(float4*)(out + i) = v;
}

// ---------------- tiled fp32 GEMM: C = A[M,K] @ W[K,N] (+bias)(+relu)(+selfinit dual write) ----
#define GBM 64
#define GBN 64
#define GBK 16
// flags: bit0 = add bias, bit1 = relu. If dinv!=nullptr: also C2[row,col] = dinv[row]^2 * v (raw, pre-bias)
__global__ __launch_bounds__(256) void k_gemm(const float* __restrict__ A,
                                              const float* __restrict__ W,
                                              const float* __restrict__ bias,
                                              float* __restrict__ C,
                                              const float* __restrict__ dinv,
                                              float* __restrict__ C2,
                                              int M, int K, int N, int flags) {
    __shared__ float As[GBK][GBM];
    __shared__ float Ws[GBK][GBN];
    int tid = threadIdx.x;
    int bm = blockIdx.x, bn = blockIdx.y;
    int tx = tid & 15, ty = tid >> 4;
    float acc[4][4] = {};

    int arow = tid >> 2;          // 0..63
    int akq  = (tid & 3) * 4;     // k offset within tile
    int wrow = tid >> 4;          // 0..15
    int wcol = (tid & 15) * 4;

    const float* Aptr = A + (size_t)(bm * GBM + arow) * K + akq;
    const float* Wptr = W + (size_t)wrow * N + (size_t)bn * GBN + wcol;

    for (int k0 = 0; k0 < K; k0 += GBK) {
        float4 av = *(const float4*)(Aptr + k0);
        float4 wv = *(const float4*)(Wptr + (size_t)k0 * N);
        As[akq + 0][arow] = av.x;
        As[akq + 1][arow] = av.y;
        As[akq + 2][arow] = av.z;
        As[akq + 3][arow] = av.w;
        *(float4*)&Ws[wrow][wcol] = wv;
        __syncthreads();
#pragma unroll
        for (int kk = 0; kk < GBK; ++kk) {
            float a0 = As[kk][ty * 4 + 0], a1 = As[kk][ty * 4 + 1];
            float a2 = As[kk][ty * 4 + 2], a3 = As[kk][ty * 4 + 3];
            float w0 = Ws[kk][tx * 4 + 0], w1 = Ws[kk][tx * 4 + 1];
            float w2 = Ws[kk][tx * 4 + 2], w3 = Ws[kk][tx * 4 + 3];
            acc[0][0] += a0 * w0; acc[0][1] += a0 * w1; acc[0][2] += a0 * w2; acc[0][3] += a0 * w3;
            acc[1][0] += a1 * w0; acc[1][1] += a1 * w1; acc[1][2] += a1 * w2; acc[1][3] += a1 * w3;
            acc[2][0] += a2 * w0; acc[2][1] += a2 * w1; acc[2][2] += a2 * w2; acc[2][3] += a2 * w3;
            acc[3][0] += a3 * w0; acc[3][1] += a3 * w1; acc[3][2] += a3 * w2; acc[3][3] += a3 * w3;
        }
        __syncthreads();
    }

#pragma unroll
    for (int i = 0; i < 4; ++i) {
        int row = bm * GBM + ty * 4 + i;
        int col = bn * GBN + tx * 4;
        float4 v = make_float4(acc[i][0], acc[i][1], acc[i][2], acc[i][3]);
        if (dinv) {
            float di = dinv[row];
            float s = di * di;
            float4 v2 = make_float4(v.x * s, v.y * s, v.z * s, v.w * s);
            *(float4*)(C2 + (size_t)row * N + col) = v2;
        }
        if (flags & 1) {
            v.x += bias[col + 0]; v.y += bias[col + 1];
            v.z += bias[col + 2]; v.w += bias[col + 3];
        }
        if (flags & 2) {
            v.x = fmaxf(v.x, 0.f); v.y = fmaxf(v.y, 0.f);
            v.z = fmaxf(v.z, 0.f); v.w = fmaxf(v.w, 0.f);
        }
        *(float4*)(C + (size_t)row * N + col) = v;
    }
}

// ---------------- tweet attention pooling (S=30, 1024 segs) ----------------
__global__ __launch_bounds__(128) void k_attpool(const float* __restrict__ x,
                                                 const float* __restrict__ gate,
                                                 float* __restrict__ out, int S) {
    const int C = 128;
    int seg = blockIdx.x;
    int c = threadIdx.x;
    size_t base = (size_t)seg * S * C + c;
    float m = -1e30f;
    for (int n = 0; n < S; ++n) m = fmaxf(m, gate[base + (size_t)n * C]);
    float se = 0.f, acc = 0.f;
    for (int n = 0; n < S; ++n) {
        float g = gate[base + (size_t)n * C];
        float e = expf(g - m);
        se += e;
        acc += e * x[base + (size_t)n * C];
    }
    out[(size_t)seg * C + c] = acc / (se + 1e-16f);
}

// ---------------- user attention pooling: chunked 4-stage (S=625, 64 segs) ----------------
// stage 1: per-chunk per-channel max
__global__ __launch_bounds__(256) void k_pool_pmax(const float* __restrict__ gate,
                                                   float* __restrict__ pmax, int S) {
    int seg = blockIdx.x, ch = blockIdx.y;
    int c = threadIdx.x & 127, j = threadIdx.x >> 7;     // j = 0,1
    int csz = (S + NCHUNK - 1) / NCHUNK;
    int n0 = ch * csz, n1 = min(S, n0 + csz);
    size_t base = (size_t)seg * S * 128 + c;
    float m = -1e30f;
    for (int n = n0 + j; n < n1; n += 2)
        m = fmaxf(m, gate[base + (size_t)n * 128]);
    __shared__ float red[2][128];
    red[j][c] = m;
    __syncthreads();
    if (j == 0)
        pmax[((size_t)seg * NCHUNK + ch) * 128 + c] = fmaxf(red[0][c], red[1][c]);
}

// stage 2: combine chunk maxes
__global__ __launch_bounds__(128) void k_pool_cmax(const float* __restrict__ pmax,
                                                   float* __restrict__ gmax) {
    int seg = blockIdx.x, c = threadIdx.x;
    float m = -1e30f;
    for (int ch = 0; ch < NCHUNK; ++ch)
        m = fmaxf(m, pmax[((size_t)seg * NCHUNK + ch) * 128 + c]);
    gmax[(size_t)seg * 128 + c] = m;
}

// stage 3: per-chunk partial sum-exp and weighted accumulation
__global__ __launch_bounds__(256) void k_pool_psum(const float* __restrict__ x,
                                                   const float* __restrict__ gate,
                                                   const float* __restrict__ gmax,
                                                   float* __restrict__ pse,
                                                   float* __restrict__ pacc, int S) {
    int seg = blockIdx.x, ch = blockIdx.y;
    int c = threadIdx.x & 127, j = threadIdx.x >> 7;
    int csz = (S + NCHUNK - 1) / NCHUNK;
    int n0 = ch * csz, n1 = min(S, n0 + csz);
    size_t base = (size_t)seg * S * 128 + c;
    float m = gmax[(size_t)seg * 128 + c];
    float se = 0.f, acc = 0.f;
    for (int n = n0 + j; n < n1; n += 2) {
        float g = gate[base + (size_t)n * 128];
        float e = expf(g - m);
        se += e;
        acc += e * x[base + (size_t)n * 128];
    }
    __shared__ float rs[2][128], ra[2][128];
    rs[j][c] = se; ra[j][c] = acc;
    __syncthreads();
    if (j == 0) {
        size_t o = ((size_t)seg * NCHUNK + ch) * 128 + c;
        pse[o]  = rs[0][c] + rs[1][c];
        pacc[o] = ra[0][c] + ra[1][c];
    }
}

// stage 4: combine partials, divide, write pooled output
__global__ __launch_bounds__(128) void k_pool_final(const float* __restrict__ pse,
                                                    const float* __restrict__ pacc,
                                                    float* __restrict__ out) {
    int seg = blockIdx.x, c = threadIdx.x;
    float se = 0.f, acc = 0.f;
    for (int ch = 0; ch < NCHUNK; ++ch) {
        size_t o = ((size_t)seg * NCHUNK + ch) * 128 + c;
        se += pse[o];
        acc += pacc[o];
    }
    out[(size_t)seg * 128 + c] = acc / (se + 1e-16f);
}

// ---------------- GRU over T=16 steps, hidden=128, one block per batch ----------------
__global__ __launch_bounds__(128) void k_gru(const float* __restrict__ seq,
                                             const float* __restrict__ Wih,
                                             const float* __restrict__ bih,
                                             const float* __restrict__ Whh,
                                             const float* __restrict__ bhh,
                                             float* __restrict__ hT) {
    __shared__ float xs[128], hs[128];
    int b = blockIdx.x, j = threadIdx.x;
    hs[j] = 0.f;
    const float* wr = Wih + (size_t)j * 128;
    const float* wz = Wih + (size_t)(128 + j) * 128;
    const float* wn = Wih + (size_t)(256 + j) * 128;
    const float* ur = Whh + (size_t)j * 128;
    const float* uz = Whh + (size_t)(128 + j) * 128;
    const float* un = Whh + (size_t)(256 + j) * 128;
    float br = bih[j], bz = bih[128 + j], bn = bih[256 + j];
    float cr = bhh[j], cz = bhh[128 + j], cn = bhh[256 + j];
    for (int t = 0; t < TT; ++t) {
        xs[j] = seq[((size_t)b * TT + t) * 128 + j];
        __syncthreads();
        float ir = br, iz = bz, in = bn, hr = cr, hz = cz, hn = cn;
        for (int k = 0; k < 128; ++k) {
            float xk = xs[k], hk = hs[k];
            ir += xk * wr[k]; iz += xk * wz[k]; in += xk * wn[k];
            hr += hk * ur[k]; hz += hk * uz[k]; hn += hk * un[k];
        }
        float r = 1.f / (1.f + expf(-(ir + hr)));
        float z = 1.f / (1.f + expf(-(iz + hz)));
        float n = tanhf(in + r * hn);
        float hnew = (1.f - z) * n + z * hs[j];
        __syncthreads();
        hs[j] = hnew;
        __syncthreads();
    }
    hT[(size_t)b * 128 + j] = hs[j];
}

// ---------------- head MLP: [32|128|128] -> 256 relu -> 64 relu -> 1 sigmoid ----------------
__global__ __launch_bounds__(256) void k_head(const float* __restrict__ uf,
                                              const float* __restrict__ up,
                                              const float* __restrict__ th,
                                              const float* __restrict__ Wd0, const float* __restrict__ bd0,
                                              const float* __restrict__ Wd1, const float* __restrict__ bd1,
                                              const float* __restrict__ Wp, const float* __restrict__ bp,
                                              float* __restrict__ out) {
    __shared__ float in0[288], l1[256], l2[64];
    int b = blockIdx.x, t = threadIdx.x;
    if (t < 32) in0[t] = uf[b * 32 + t];
    else if (t < 160) in0[t] = up[b * 128 + (t - 32)];
    if (t < 128) in0[160 + t] = th[b * 128 + t];
    __syncthreads();
    float acc = bd0[t];
    for (int k = 0; k < 288; ++k) acc += in0[k] * Wd0[k * 256 + t];
    l1[t] = fmaxf(acc, 0.f);
    __syncthreads();
    if (t < 64) {
        float a2 = bd1[t];
        for (int k = 0; k < 256; ++k) a2 += l1[k] * Wd1[k * 64 + t];
        l2[t] = fmaxf(a2, 0.f);
    }
    __syncthreads();
    if (t < 64) {
        float p = l2[t] * Wp[t];
        for (int off = 32; off; off >>= 1) p += __shfl_down(p, off, 64);
        if (t == 0) out[b] = 1.f / (1.f + expf(-(p + bp[0])));
    }
}

// ---------------- launch ----------------
extern "C" void kernel_launch(void* const* d_in, const int* in_sizes, int n_in,
                              void* d_out, int out_size, void* d_ws, size_t ws_size,
                              hipStream_t stream) {
    const float* user_x     = (const float*)d_in[0];
    const float* user_feats = (const float*)d_in[1];
    const float* tweet_x    = (const float*)d_in[2];
    const float* Wu0 = (const float*)d_in[3];  const float* bu0 = (const float*)d_in[4];
    const float* Wu1 = (const float*)d_in[5];  const float* bu1 = (const float*)d_in[6];
    const float* Wgu1 = (const float*)d_in[7]; const float* bgu1 = (const float*)d_in[8];
    const float* Wgu2 = (const float*)d_in[9]; const float* bgu2 = (const float*)d_in[10];
    const float* Wt0 = (const float*)d_in[11]; const float* bt0 = (const float*)d_in[12];
    const float* Wt1 = (const float*)d_in[13]; const float* bt1 = (const float*)d_in[14];
    const float* Wgt1 = (const float*)d_in[15]; const float* bgt1 = (const float*)d_in[16];
    const float* Wgt2 = (const float*)d_in[17]; const float* bgt2 = (const float*)d_in[18];
    const float* W_ih = (const float*)d_in[19]; const float* b_ih = (const float*)d_in[20];
    const float* W_hh = (const float*)d_in[21]; const float* b_hh = (const float*)d_in[22];
    const float* Wd0 = (const float*)d_in[23]; const float* bd0 = (const float*)d_in[24];
    const float* Wd1 = (const float*)d_in[25]; const float* bd1 = (const float*)d_in[26];
    const float* Wp  = (const float*)d_in[27]; const float* bp  = (const float*)d_in[28];
    const int* ue = (const int*)d_in[29];           // [2, EU]
    const int* te = (const int*)d_in[30];           // [2, NTE]
    const int* ue_src = ue, *ue_dst = ue + EU;
    const int* te_src = te, *te_dst = te + NTE;

    float* ws = (float*)d_ws;
    // region0 (shared between branches): tweet needs 2*NT*256 = 15,728,640 floats
    // user bufs (3 * NU*128 = 15,360,000 floats) alias into the same region.
    float* region0 = ws;
    const size_t R0 = (size_t)NTNODES * 256 * 2;
    float* bufA = region0;
    float* bufB = region0 + (size_t)NU * 128;
    float* bufC = region0 + (size_t)NU * 128 * 2;
    float* tA = region0;
    float* tB = region0 + (size_t)NTNODES * 256;
    size_t o = R0;
    float* dinv_u = ws + o;     o += NU;
    float* dinv_t = ws + o;     o += NTNODES;   // contiguous after dinv_u (k_count2 relies on it)
    float* user_pool = ws + o;  o += (size_t)BB * 128;
    float* tweet_pool = ws + o; o += (size_t)NSEG_T * 128;
    float* tweet_h = ws + o;    o += (size_t)BB * 128;
    float* out = (float*)d_out;

    // pool partials alias dead bufA region (free during user att-pool)
    float* pmax = bufA;                       // 64*16*128
    float* pse  = bufA + 131072;              // 64*16*128
    float* pacc = bufA + 262144;              // 64*16*128
    float* gmax = bufA + 393216;              // 64*128

    // ---- degrees (user+tweet fused) ----
    hipLaunchKernelGGL(k_fill1, dim3((NU + NTNODES + 255) / 256), dim3(256), 0, stream,
                       dinv_u, NU + NTNODES);
    hipLaunchKernelGGL(k_count2, dim3((EU + NTE + 255) / 256), dim3(256), 0, stream,
                       ue_dst, te_dst, dinv_u, dinv_t);
    hipLaunchKernelGGL(k_rsqrt, dim3((NU + NTNODES + 255) / 256), dim3(256), 0, stream,
                       dinv_u, NU + NTNODES);

    const long U128 = (long)NU * 128;
    const long T256 = (long)NTNODES * 256;
    const long T128 = (long)NTNODES * 128;
    dim3 b256(256);
    dim3 gU128((U128 / 4 + 255) / 256), gT256((T256 / 4 + 255) / 256), gT128((T128 / 4 + 255) / 256);
    const float* NOD = nullptr;  // no dual write
    float* NOC = nullptr;

    // ---- user branch ----
    // conv1: bufA = user_x@Wu0, bufB = dinv^2*bufA (fused self-init)
    hipLaunchKernelGGL(k_gemm, dim3(NU / GBM, 128 / GBN), b256, 0, stream,
                       user_x, Wu0, NOD, bufA, dinv_u, bufB, NU, 128, 128, 0);
    hipLaunchKernelGGL(k_scatter, dim3((EU + 3) / 4), b256, 0, stream,
                       ue_src, ue_dst, dinv_u, bufA, bufB, EU, 128);
    hipLaunchKernelGGL(k_biasrelu, gU128, b256, 0, stream, bufB, bu0, U128, 128);
    // conv2: bufA = bufB@Wu1, bufC = dinv^2*bufA
    hipLaunchKernelGGL(k_gemm, dim3(NU / GBM, 128 / GBN), b256, 0, stream,
                       bufB, Wu1, NOD, bufA, dinv_u, bufC, NU, 128, 128, 0);
    hipLaunchKernelGGL(k_scatter, dim3((EU + 3) / 4), b256, 0, stream,
                       ue_src, ue_dst, dinv_u, bufA, bufC, EU, 128);
    hipLaunchKernelGGL(k_biasrelu, gU128, b256, 0, stream, bufC, bu1, U128, 128);
    // gate
    hipLaunchKernelGGL(k_gemm, dim3(NU / GBM, 128 / GBN), b256, 0, stream,
                       bufC, Wgu1, bgu1, bufA, NOD, NOC, NU, 128, 128, 1);
    hipLaunchKernelGGL(k_gemm, dim3(NU / GBM, 128 / GBN), b256, 0, stream,
                       bufA, Wgu2, bgu2, bufB, NOD, NOC, NU, 128, 128, 1);
    // chunked pool (partials alias bufA — safe, gate GEMMs done with it)
    hipLaunchKernelGGL(k_pool_pmax, dim3(BB, NCHUNK), b256, 0, stream, bufB, pmax, NU / BB);
    hipLaunchKernelGGL(k_pool_cmax, dim3(BB), dim3(128), 0, stream, pmax, gmax);
    hipLaunchKernelGGL(k_pool_psum, dim3(BB, NCHUNK), b256, 0, stream,
                       bufC, bufB, gmax, pse, pacc, NU / BB);
    hipLaunchKernelGGL(k_pool_final, dim3(BB), dim3(128), 0, stream, pse, pacc, user_pool);

    // ---- tweet branch ----
    // conv1 (768 -> 256): tA = tweet_x@Wt0, tB = dinv^2*tA
    hipLaunchKernelGGL(k_gemm, dim3(NTNODES / GBM, 256 / GBN), b256, 0, stream,
                       tweet_x, Wt0, NOD, tA, dinv_t, tB, NTNODES, 768, 256, 0);
    hipLaunchKernelGGL(k_scatter, dim3((NTE + 3) / 4), b256, 0, stream,
                       te_src, te_dst, dinv_t, tA, tB, NTE, 256);
    hipLaunchKernelGGL(k_biasrelu, gT256, b256, 0, stream, tB, bt0, T256, 256);
    // conv2 (256 -> 128): tA = tB@Wt1, tB2 = dinv^2*tA  (write into tA-half region is unsafe; reuse tB? no —
    //   tB holds conv1 output until GEMM reads it fully; use separate: write y into tA, scaled into tA+T128 is
    //   also fine, but scatter output must not alias y. Use tA (y) and tB (out) — tB is being read by the GEMM.
    //   So: y -> tA, scaled -> tA + T128 (free: tA region is 2*T256 total? tA half = NT*256; T128*2 fits).
    hipLaunchKernelGGL(k_gemm, dim3(NTNODES / GBM, 128 / GBN), b256, 0, stream,
                       tB, Wt1, NOD, tA, dinv_t, tA + T128, NTNODES, 256, 128, 0);
    hipLaunchKernelGGL(k_scatter, dim3((NTE + 3) / 4), b256, 0, stream,
                       te_src, te_dst, dinv_t, tA, tA + T128, NTE, 128);
    hipLaunchKernelGGL(k_biasrelu, gT128, b256, 0, stream, tA + T128, bt1, T128, 128);
    float* g2 = tA + T128;      // conv2 output [NT,128]
    // gate
    hipLaunchKernelGGL(k_gemm, dim3(NTNODES / GBM, 128 / GBN), b256, 0, stream,
                       g2, Wgt1, bgt1, tB, NOD, NOC, NTNODES, 128, 128, 1);
    hipLaunchKernelGGL(k_gemm, dim3(NTNODES / GBM, 128 / GBN), b256, 0, stream,
                       tB, Wgt2, bgt2, tA, NOD, NOC, NTNODES, 128, 128, 1);
    hipLaunchKernelGGL(k_attpool, dim3(NSEG_T), dim3(128), 0, stream, g2, tA, tweet_pool, NW);

    // ---- GRU ----
    hipLaunchKernelGGL(k_gru, dim3(BB), dim3(128), 0, stream,
                       tweet_pool, W_ih, b_ih, W_hh, b_hh, tweet_h);

    // ---- head ----
    hipLaunchKernelGGL(k_head, dim3(BB), b256, 0, stream,
                       user_feats, user_pool, tweet_h,
                       Wd0, bd0, Wd1, bd1, Wp, bp, out);
}

// Round 3
// 969.903 us; speedup vs baseline: 1.6575x; 1.3739x over previous
//
#include <hip/hip_runtime.h>
#include <hip/hip_bf16.h>

// ---------------- problem constants ----------------
#define NU 40000
#define EU 640000
#define BB 64
#define TT 16
#define NW 30
#define NTNODES 30720       // B*T*NW
#define NTE 61440           // tweet edges
#define NSEG_T 1024         // B*T
#define NCHUNK 16           // chunks per user segment for att-pool

// ---------------- degree / CSR build kernels ----------------
__global__ void k_zeroint(int* __restrict__ p, int n) {
    int i = blockIdx.x * blockDim.x + threadIdx.x;
    if (i < n) p[i] = 0;
}

// int histogram of destinations (user + tweet fused; hist_t = hist_u + NU)
__global__ void k_hist2(const int* __restrict__ ue_dst, const int* __restrict__ te_dst,
                        int* __restrict__ hist_u, int* __restrict__ hist_t) {
    int i = blockIdx.x * blockDim.x + threadIdx.x;
    if (i < EU) atomicAdd(&hist_u[ue_dst[i]], 1);
    else if (i < EU + NTE) atomicAdd(&hist_t[te_dst[i - EU]], 1);
}

// dinv[i] = rsqrt(hist[i] + 1)   (self-loop included)
__global__ void k_dinv(const int* __restrict__ hist, float* __restrict__ dinv, int n) {
    int i = blockIdx.x * blockDim.x + threadIdx.x;
    if (i < n) dinv[i] = rsqrtf((float)hist[i] + 1.0f);
}

// single-block exclusive scan: hist[0..n) -> ptr[0..n]
__global__ __launch_bounds__(1024) void k_scan(const int* __restrict__ hist,
                                               int* __restrict__ ptr, int n) {
    __shared__ int sums[1024];
    int t = threadIdx.x;
    int chunk = (n + 1023) / 1024;
    int lo = t * chunk, hi = min(n, lo + chunk);
    int s = 0;
    for (int i = lo; i < hi; ++i) s += hist[i];
    sums[t] = s;
    __syncthreads();
    for (int off = 1; off < 1024; off <<= 1) {
        int v = (t >= off) ? sums[t - off] : 0;
        __syncthreads();
        sums[t] += v;
        __syncthreads();
    }
    int base = (t == 0) ? 0 : sums[t - 1];
    for (int i = lo; i < hi; ++i) {
        ptr[i] = base;
        base += hist[i];
    }
    if (t == 1023) ptr[n] = base;
}

__global__ void k_copyint(const int* __restrict__ a, int* __restrict__ b, int n) {
    int i = blockIdx.x * blockDim.x + threadIdx.x;
    if (i < n) b[i] = a[i];
}

// place edges into dst-sorted order: esrc[pos] = src[e]
__global__ void k_place(const int* __restrict__ src, const int* __restrict__ dst,
                        int* __restrict__ fill, int* __restrict__ esrc, int E) {
    int e = blockIdx.x * blockDim.x + threadIdx.x;
    if (e >= E) return;
    int d = dst[e];
    int pos = atomicAdd(&fill[d], 1);
    esrc[pos] = src[e];
}

// ---------------- CSR gather-aggregation (C=128, fused self-loop+bias+relu) ----------------
// out[v,:] = relu( dinv[v]^2*y[v,:] + sum_e dinv[v]*dinv[src]*y[src,:] + b )
__global__ __launch_bounds__(256) void k_gagg(const float* __restrict__ y,
                                              const int* __restrict__ ptr,
                                              const int* __restrict__ esrc,
                                              const float* __restrict__ dinv,
                                              const float* __restrict__ bias,
                                              float* __restrict__ outbuf, int N) {
    int v = blockIdx.x * 4 + (threadIdx.x >> 6);
    if (v >= N) return;
    int lane = threadIdx.x & 63;
    float dv = dinv[v];
    const float* yv = y + (size_t)v * 128;
    float a0 = dv * dv * yv[lane];
    float a1 = dv * dv * yv[lane + 64];
    int e = ptr[v], e1 = ptr[v + 1];
    // unroll-by-2 for memory-level parallelism
    for (; e + 1 < e1; e += 2) {
        int s0 = esrc[e], s1 = esrc[e + 1];
        float c0 = dv * dinv[s0], c1 = dv * dinv[s1];
        const float* ys0 = y + (size_t)s0 * 128;
        const float* ys1 = y + (size_t)s1 * 128;
        a0 += c0 * ys0[lane];
        a1 += c0 * ys0[lane + 64];
        a0 += c1 * ys1[lane];
        a1 += c1 * ys1[lane + 64];
    }
    if (e < e1) {
        int s0 = esrc[e];
        float c0 = dv * dinv[s0];
        const float* ys0 = y + (size_t)s0 * 128;
        a0 += c0 * ys0[lane];
        a1 += c0 * ys0[lane + 64];
    }
    a0 = fmaxf(a0 + bias[lane], 0.f);
    a1 = fmaxf(a1 + bias[lane + 64], 0.f);
    float* o = outbuf + (size_t)v * 128;
    o[lane] = a0;
    o[lane + 64] = a1;
}

// ---------------- atomic scatter (tweet branch): out[d,:] += dinv[s]*dinv[d]*y[s,:] ----------
__global__ __launch_bounds__(256) void k_scatter(const int* __restrict__ src,
                                                 const int* __restrict__ dst,
                                                 const float* __restrict__ dinv,
                                                 const float* __restrict__ y,
                                                 float* __restrict__ out, int E, int C) {
    int e = blockIdx.x * (blockDim.x >> 6) + (threadIdx.x >> 6);
    if (e >= E) return;
    int lane = threadIdx.x & 63;
    int s = src[e], d = dst[e];
    float coef = dinv[s] * dinv[d];
    const float* yr = y + (size_t)s * C;
    float* orow = out + (size_t)d * C;
    for (int c = lane; c < C; c += 64)
        atomicAdd(&orow[c], coef * yr[c]);
}

// out = relu(out + bias[c])   (float4)
__global__ void k_biasrelu(float* __restrict__ out, const float* __restrict__ b,
                           long total, int C) {
    long i = ((long)blockIdx.x * blockDim.x + threadIdx.x) * 4;
    if (i >= total) return;
    int c = (int)(i % C);
    float4 v = *(float4*)(out + i);
    v.x = fmaxf(v.x + b[c + 0], 0.f);
    v.y = fmaxf(v.y + b[c + 1], 0.f);
    v.z = fmaxf(v.z + b[c + 2], 0.f);
    v.w = fmaxf(v.w + b[c + 3], 0.f);
    *(float4*)(out + i) = v;
}

// ---------------- tiled fp32 GEMM: C = A[M,K] @ W[K,N] (+bias)(+relu)(+selfinit dual write) ----
#define GBM 64
#define GBN 64
#define GBK 16
// flags: bit0 = add bias, bit1 = relu. If dinv!=nullptr: also C2[row,col] = dinv[row]^2 * v (raw, pre-bias)
__global__ __launch_bounds__(256) void k_gemm(const float* __restrict__ A,
                                              const float* __restrict__ W,
                                              const float* __restrict__ bias,
                                              float* __restrict__ C,
                                              const float* __restrict__ dinv,
                                              float* __restrict__ C2,
                                              int M, int K, int N, int flags) {
    __shared__ float As[GBK][GBM];
    __shared__ float Ws[GBK][GBN];
    int tid = threadIdx.x;
    int bm = blockIdx.x, bn = blockIdx.y;
    int tx = tid & 15, ty = tid >> 4;
    float acc[4][4] = {};

    int arow = tid >> 2;
    int akq  = (tid & 3) * 4;
    int wrow = tid >> 4;
    int wcol = (tid & 15) * 4;

    const float* Aptr = A + (size_t)(bm * GBM + arow) * K + akq;
    const float* Wptr = W + (size_t)wrow * N + (size_t)bn * GBN + wcol;

    for (int k0 = 0; k0 < K; k0 += GBK) {
        float4 av = *(const float4*)(Aptr + k0);
        float4 wv = *(const float4*)(Wptr + (size_t)k0 * N);
        As[akq + 0][arow] = av.x;
        As[akq + 1][arow] = av.y;
        As[akq + 2][arow] = av.z;
        As[akq + 3][arow] = av.w;
        *(float4*)&Ws[wrow][wcol] = wv;
        __syncthreads();
#pragma unroll
        for (int kk = 0; kk < GBK; ++kk) {
            float a0 = As[kk][ty * 4 + 0], a1 = As[kk][ty * 4 + 1];
            float a2 = As[kk][ty * 4 + 2], a3 = As[kk][ty * 4 + 3];
            float w0 = Ws[kk][tx * 4 + 0], w1 = Ws[kk][tx * 4 + 1];
            float w2 = Ws[kk][tx * 4 + 2], w3 = Ws[kk][tx * 4 + 3];
            acc[0][0] += a0 * w0; acc[0][1] += a0 * w1; acc[0][2] += a0 * w2; acc[0][3] += a0 * w3;
            acc[1][0] += a1 * w0; acc[1][1] += a1 * w1; acc[1][2] += a1 * w2; acc[1][3] += a1 * w3;
            acc[2][0] += a2 * w0; acc[2][1] += a2 * w1; acc[2][2] += a2 * w2; acc[2][3] += a2 * w3;
            acc[3][0] += a3 * w0; acc[3][1] += a3 * w1; acc[3][2] += a3 * w2; acc[3][3] += a3 * w3;
        }
        __syncthreads();
    }

#pragma unroll
    for (int i = 0; i < 4; ++i) {
        int row = bm * GBM + ty * 4 + i;
        int col = bn * GBN + tx * 4;
        float4 v = make_float4(acc[i][0], acc[i][1], acc[i][2], acc[i][3]);
        if (dinv) {
            float di = dinv[row];
            float s = di * di;
            float4 v2 = make_float4(v.x * s, v.y * s, v.z * s, v.w * s);
            *(float4*)(C2 + (size_t)row * N + col) = v2;
        }
        if (flags & 1) {
            v.x += bias[col + 0]; v.y += bias[col + 1];
            v.z += bias[col + 2]; v.w += bias[col + 3];
        }
        if (flags & 2) {
            v.x = fmaxf(v.x, 0.f); v.y = fmaxf(v.y, 0.f);
            v.z = fmaxf(v.z, 0.f); v.w = fmaxf(v.w, 0.f);
        }
        *(float4*)(C + (size_t)row * N + col) = v;
    }
}

// ---------------- tweet attention pooling (S=30, 1024 segs) ----------------
__global__ __launch_bounds__(128) void k_attpool(const float* __restrict__ x,
                                                 const float* __restrict__ gate,
                                                 float* __restrict__ out, int S) {
    const int C = 128;
    int seg = blockIdx.x;
    int c = threadIdx.x;
    size_t base = (size_t)seg * S * C + c;
    float m = -1e30f;
    for (int n = 0; n < S; ++n) m = fmaxf(m, gate[base + (size_t)n * C]);
    float se = 0.f, acc = 0.f;
    for (int n = 0; n < S; ++n) {
        float g = gate[base + (size_t)n * C];
        float e = expf(g - m);
        se += e;
        acc += e * x[base + (size_t)n * C];
    }
    out[(size_t)seg * C + c] = acc / (se + 1e-16f);
}

// ---------------- user attention pooling: chunked 4-stage (S=625, 64 segs) ----------------
__global__ __launch_bounds__(256) void k_pool_pmax(const float* __restrict__ gate,
                                                   float* __restrict__ pmax, int S) {
    int seg = blockIdx.x, ch = blockIdx.y;
    int c = threadIdx.x & 127, j = threadIdx.x >> 7;
    int csz = (S + NCHUNK - 1) / NCHUNK;
    int n0 = ch * csz, n1 = min(S, n0 + csz);
    size_t base = (size_t)seg * S * 128 + c;
    float m = -1e30f;
    for (int n = n0 + j; n < n1; n += 2)
        m = fmaxf(m, gate[base + (size_t)n * 128]);
    __shared__ float red[2][128];
    red[j][c] = m;
    __syncthreads();
    if (j == 0)
        pmax[((size_t)seg * NCHUNK + ch) * 128 + c] = fmaxf(red[0][c], red[1][c]);
}

__global__ __launch_bounds__(128) void k_pool_cmax(const float* __restrict__ pmax,
                                                   float* __restrict__ gmax) {
    int seg = blockIdx.x, c = threadIdx.x;
    float m = -1e30f;
    for (int ch = 0; ch < NCHUNK; ++ch)
        m = fmaxf(m, pmax[((size_t)seg * NCHUNK + ch) * 128 + c]);
    gmax[(size_t)seg * 128 + c] = m;
}

__global__ __launch_bounds__(256) void k_pool_psum(const float* __restrict__ x,
                                                   const float* __restrict__ gate,
                                                   const float* __restrict__ gmax,
                                                   float* __restrict__ pse,
                                                   float* __restrict__ pacc, int S) {
    int seg = blockIdx.x, ch = blockIdx.y;
    int c = threadIdx.x & 127, j = threadIdx.x >> 7;
    int csz = (S + NCHUNK - 1) / NCHUNK;
    int n0 = ch * csz, n1 = min(S, n0 + csz);
    size_t base = (size_t)seg * S * 128 + c;
    float m = gmax[(size_t)seg * 128 + c];
    float se = 0.f, acc = 0.f;
    for (int n = n0 + j; n < n1; n += 2) {
        float g = gate[base + (size_t)n * 128];
        float e = expf(g - m);
        se += e;
        acc += e * x[base + (size_t)n * 128];
    }
    __shared__ float rs[2][128], ra[2][128];
    rs[j][c] = se; ra[j][c] = acc;
    __syncthreads();
    if (j == 0) {
        size_t o = ((size_t)seg * NCHUNK + ch) * 128 + c;
        pse[o]  = rs[0][c] + rs[1][c];
        pacc[o] = ra[0][c] + ra[1][c];
    }
}

__global__ __launch_bounds__(128) void k_pool_final(const float* __restrict__ pse,
                                                    const float* __restrict__ pacc,
                                                    float* __restrict__ out) {
    int seg = blockIdx.x, c = threadIdx.x;
    float se = 0.f, acc = 0.f;
    for (int ch = 0; ch < NCHUNK; ++ch) {
        size_t o = ((size_t)seg * NCHUNK + ch) * 128 + c;
        se += pse[o];
        acc += pacc[o];
    }
    out[(size_t)seg * 128 + c] = acc / (se + 1e-16f);
}

// ---------------- GRU over T=16 steps, hidden=128, one block per batch ----------------
__global__ __launch_bounds__(128) void k_gru(const float* __restrict__ seq,
                                             const float* __restrict__ Wih,
                                             const float* __restrict__ bih,
                                             const float* __restrict__ Whh,
                                             const float* __restrict__ bhh,
                                             float* __restrict__ hT) {
    __shared__ float xs[128], hs[128];
    int b = blockIdx.x, j = threadIdx.x;
    hs[j] = 0.f;
    const float* wr = Wih + (size_t)j * 128;
    const float* wz = Wih + (size_t)(128 + j) * 128;
    const float* wn = Wih + (size_t)(256 + j) * 128;
    const float* ur = Whh + (size_t)j * 128;
    const float* uz = Whh + (size_t)(128 + j) * 128;
    const float* un = Whh + (size_t)(256 + j) * 128;
    float br = bih[j], bz = bih[128 + j], bn = bih[256 + j];
    float cr = bhh[j], cz = bhh[128 + j], cn = bhh[256 + j];
    for (int t = 0; t < TT; ++t) {
        xs[j] = seq[((size_t)b * TT + t) * 128 + j];
        __syncthreads();
        float ir = br, iz = bz, in = bn, hr = cr, hz = cz, hn = cn;
        for (int k = 0; k < 128; ++k) {
            float xk = xs[k], hk = hs[k];
            ir += xk * wr[k]; iz += xk * wz[k]; in += xk * wn[k];
            hr += hk * ur[k]; hz += hk * uz[k]; hn += hk * un[k];
        }
        float r = 1.f / (1.f + expf(-(ir + hr)));
        float z = 1.f / (1.f + expf(-(iz + hz)));
        float n = tanhf(in + r * hn);
        float hnew = (1.f - z) * n + z * hs[j];
        __syncthreads();
        hs[j] = hnew;
        __syncthreads();
    }
    hT[(size_t)b * 128 + j] = hs[j];
}

// ---------------- head MLP ----------------
__global__ __launch_bounds__(256) void k_head(const float* __restrict__ uf,
                                              const float* __restrict__ up,
                                              const float* __restrict__ th,
                                              const float* __restrict__ Wd0, const float* __restrict__ bd0,
                                              const float* __restrict__ Wd1, const float* __restrict__ bd1,
                                              const float* __restrict__ Wp, const float* __restrict__ bp,
                                              float* __restrict__ out) {
    __shared__ float in0[288], l1[256], l2[64];
    int b = blockIdx.x, t = threadIdx.x;
    if (t < 32) in0[t] = uf[b * 32 + t];
    else if (t < 160) in0[t] = up[b * 128 + (t - 32)];
    if (t < 128) in0[160 + t] = th[b * 128 + t];
    __syncthreads();
    float acc = bd0[t];
    for (int k = 0; k < 288; ++k) acc += in0[k] * Wd0[k * 256 + t];
    l1[t] = fmaxf(acc, 0.f);
    __syncthreads();
    if (t < 64) {
        float a2 = bd1[t];
        for (int k = 0; k < 256; ++k) a2 += l1[k] * Wd1[k * 64 + t];
        l2[t] = fmaxf(a2, 0.f);
    }
    __syncthreads();
    if (t < 64) {
        float p = l2[t] * Wp[t];
        for (int off = 32; off; off >>= 1) p += __shfl_down(p, off, 64);
        if (t == 0) out[b] = 1.f / (1.f + expf(-(p + bp[0])));
    }
}

// ---------------- launch ----------------
extern "C" void kernel_launch(void* const* d_in, const int* in_sizes, int n_in,
                              void* d_out, int out_size, void* d_ws, size_t ws_size,
                              hipStream_t stream) {
    const float* user_x     = (const float*)d_in[0];
    const float* user_feats = (const float*)d_in[1];
    const float* tweet_x    = (const float*)d_in[2];
    const float* Wu0 = (const float*)d_in[3];  const float* bu0 = (const float*)d_in[4];
    const float* Wu1 = (const float*)d_in[5];  const float* bu1 = (const float*)d_in[6];
    const float* Wgu1 = (const float*)d_in[7]; const float* bgu1 = (const float*)d_in[8];
    const float* Wgu2 = (const float*)d_in[9]; const float* bgu2 = (const float*)d_in[10];
    const float* Wt0 = (const float*)d_in[11]; const float* bt0 = (const float*)d_in[12];
    const float* Wt1 = (const float*)d_in[13]; const float* bt1 = (const float*)d_in[14];
    const float* Wgt1 = (const float*)d_in[15]; const float* bgt1 = (const float*)d_in[16];
    const float* Wgt2 = (const float*)d_in[17]; const float* bgt2 = (const float*)d_in[18];
    const float* W_ih = (const float*)d_in[19]; const float* b_ih = (const float*)d_in[20];
    const float* W_hh = (const float*)d_in[21]; const float* b_hh = (const float*)d_in[22];
    const float* Wd0 = (const float*)d_in[23]; const float* bd0 = (const float*)d_in[24];
    const float* Wd1 = (const float*)d_in[25]; const float* bd1 = (const float*)d_in[26];
    const float* Wp  = (const float*)d_in[27]; const float* bp  = (const float*)d_in[28];
    const int* ue = (const int*)d_in[29];           // [2, EU]
    const int* te = (const int*)d_in[30];           // [2, NTE]
    const int* ue_src = ue, *ue_dst = ue + EU;
    const int* te_src = te, *te_dst = te + NTE;

    float* ws = (float*)d_ws;
    float* region0 = ws;
    const size_t R0 = (size_t)NTNODES * 256 * 2;   // 15,728,640 floats
    float* bufA = region0;
    float* bufB = region0 + (size_t)NU * 128;
    float* bufC = region0 + (size_t)NU * 128 * 2;
    float* tA = region0;
    float* tB = region0 + (size_t)NTNODES * 256;
    size_t o = R0;
    float* dinv_u = ws + o;     o += NU;
    float* dinv_t = ws + o;     o += NTNODES;   // contiguous after dinv_u
    float* user_pool = ws + o;  o += (size_t)BB * 128;
    float* tweet_pool = ws + o; o += (size_t)NSEG_T * 128;
    float* tweet_h = ws + o;    o += (size_t)BB * 128;
    // int arrays after the float region
    int* iw = (int*)(ws + o);
    int* hist_u = iw;                      // NU   (hist_t contiguous after)
    int* hist_t = iw + NU;                 // NTNODES
    int* ptr_u  = iw + NU + NTNODES;       // NU+1
    int* fill_u = ptr_u + NU + 1;          // NU
    int* esrc_u = fill_u + NU;             // EU
    float* out = (float*)d_out;

    // pool partials alias dead bufA region during user att-pool
    float* pmax = bufA;
    float* pse  = bufA + 131072;
    float* pacc = bufA + 262144;
    float* gmax = bufA + 393216;

    dim3 b256(256);

    // ---- degrees + user CSR ----
    hipLaunchKernelGGL(k_zeroint, dim3((NU + NTNODES + 255) / 256), b256, 0, stream,
                       hist_u, NU + NTNODES);
    hipLaunchKernelGGL(k_hist2, dim3((EU + NTE + 255) / 256), b256, 0, stream,
                       ue_dst, te_dst, hist_u, hist_t);
    hipLaunchKernelGGL(k_dinv, dim3((NU + NTNODES + 255) / 256), b256, 0, stream,
                       hist_u, dinv_u, NU + NTNODES);
    hipLaunchKernelGGL(k_scan, dim3(1), dim3(1024), 0, stream, hist_u, ptr_u, NU);
    hipLaunchKernelGGL(k_copyint, dim3((NU + 255) / 256), b256, 0, stream, ptr_u, fill_u, NU);
    hipLaunchKernelGGL(k_place, dim3((EU + 255) / 256), b256, 0, stream,
                       ue_src, ue_dst, fill_u, esrc_u, EU);

    const long T256 = (long)NTNODES * 256;
    const long T128 = (long)NTNODES * 128;
    dim3 gT256((T256 / 4 + 255) / 256), gT128((T128 / 4 + 255) / 256);
    const float* NOD = nullptr;
    float* NOC = nullptr;

    // ---- user branch (CSR gather aggregation, fused bias+relu) ----
    // conv1: y1 = user_x@Wu0 -> bufA ; h1 = agg(bufA) -> bufB
    hipLaunchKernelGGL(k_gemm, dim3(NU / GBM, 128 / GBN), b256, 0, stream,
                       user_x, Wu0, NOD, bufA, NOD, NOC, NU, 128, 128, 0);
    hipLaunchKernelGGL(k_gagg, dim3((NU + 3) / 4), b256, 0, stream,
                       bufA, ptr_u, esrc_u, dinv_u, bu0, bufB, NU);
    // conv2: y2 = h1@Wu1 -> bufA ; h2 = agg(bufA) -> bufC
    hipLaunchKernelGGL(k_gemm, dim3(NU / GBM, 128 / GBN), b256, 0, stream,
                       bufB, Wu1, NOD, bufA, NOD, NOC, NU, 128, 128, 0);
    hipLaunchKernelGGL(k_gagg, dim3((NU + 3) / 4), b256, 0, stream,
                       bufA, ptr_u, esrc_u, dinv_u, bu1, bufC, NU);
    // gate: g1 = h2@Wgu1+b -> bufA ; gate = g1@Wgu2+b -> bufB
    hipLaunchKernelGGL(k_gemm, dim3(NU / GBM, 128 / GBN), b256, 0, stream,
                       bufC, Wgu1, bgu1, bufA, NOD, NOC, NU, 128, 128, 1);
    hipLaunchKernelGGL(k_gemm, dim3(NU / GBM, 128 / GBN), b256, 0, stream,
                       bufA, Wgu2, bgu2, bufB, NOD, NOC, NU, 128, 128, 1);
    // chunked pool (partials alias bufA — gate GEMMs done with it)
    hipLaunchKernelGGL(k_pool_pmax, dim3(BB, NCHUNK), b256, 0, stream, bufB, pmax, NU / BB);
    hipLaunchKernelGGL(k_pool_cmax, dim3(BB), dim3(128), 0, stream, pmax, gmax);
    hipLaunchKernelGGL(k_pool_psum, dim3(BB, NCHUNK), b256, 0, stream,
                       bufC, bufB, gmax, pse, pacc, NU / BB);
    hipLaunchKernelGGL(k_pool_final, dim3(BB), dim3(128), 0, stream, pse, pacc, user_pool);

    // ---- tweet branch (unchanged: atomic scatter, dual-write GEMM) ----
    hipLaunchKernelGGL(k_gemm, dim3(NTNODES / GBM, 256 / GBN), b256, 0, stream,
                       tweet_x, Wt0, NOD, tA, dinv_t, tB, NTNODES, 768, 256, 0);
    hipLaunchKernelGGL(k_scatter, dim3((NTE + 3) / 4), b256, 0, stream,
                       te_src, te_dst, dinv_t, tA, tB, NTE, 256);
    hipLaunchKernelGGL(k_biasrelu, gT256, b256, 0, stream, tB, bt0, T256, 256);
    hipLaunchKernelGGL(k_gemm, dim3(NTNODES / GBM, 128 / GBN), b256, 0, stream,
                       tB, Wt1, NOD, tA, dinv_t, tA + T128, NTNODES, 256, 128, 0);
    hipLaunchKernelGGL(k_scatter, dim3((NTE + 3) / 4), b256, 0, stream,
                       te_src, te_dst, dinv_t, tA, tA + T128, NTE, 128);
    hipLaunchKernelGGL(k_biasrelu, gT128, b256, 0, stream, tA + T128, bt1, T128, 128);
    float* g2 = tA + T128;
    hipLaunchKernelGGL(k_gemm, dim3(NTNODES / GBM, 128 / GBN), b256, 0, stream,
                       g2, Wgt1, bgt1, tB, NOD, NOC, NTNODES, 128, 128, 1);
    hipLaunchKernelGGL(k_gemm, dim3(NTNODES / GBM, 128 / GBN), b256, 0, stream,
                       tB, Wgt2, bgt2, tA, NOD, NOC, NTNODES, 128, 128, 1);
    hipLaunchKernelGGL(k_attpool, dim3(NSEG_T), dim3(128), 0, stream, g2, tA, tweet_pool, NW);

    // ---- GRU ----
    hipLaunchKernelGGL(k_gru, dim3(BB), dim3(128), 0, stream,
                       tweet_pool, W_ih, b_ih, W_hh, b_hh, tweet_h);

    // ---- head ----
    hipLaunchKernelGGL(k_head, dim3(BB), b256, 0, stream,
                       user_feats, user_pool, tweet_h,
                       Wd0, bd0, Wd1, bd1, Wp, bp, out);
}

// Round 4
// 763.174 us; speedup vs baseline: 2.1065x; 1.2709x over previous
//
#include <hip/hip_runtime.h>
#include <hip/hip_bf16.h>

// ---------------- problem constants ----------------
#define NU 40000
#define EU 640000
#define BB 64
#define TT 16
#define NW 30
#define NTNODES 30720       // B*T*NW
#define NTE 61440           // tweet edges
#define NSEG_T 1024         // B*T
#define NCHUNK 16           // chunks per user segment for att-pool

// ---------------- degree / CSR build kernels ----------------
__global__ void k_zeroint(int* __restrict__ p, int n) {
    int i = blockIdx.x * blockDim.x + threadIdx.x;
    if (i < n) p[i] = 0;
}

// int histogram of destinations (user + tweet fused; hist_t = hist_u + NU)
__global__ void k_hist2(const int* __restrict__ ue_dst, const int* __restrict__ te_dst,
                        int* __restrict__ hist_u, int* __restrict__ hist_t) {
    int i = blockIdx.x * blockDim.x + threadIdx.x;
    if (i < EU) atomicAdd(&hist_u[ue_dst[i]], 1);
    else if (i < EU + NTE) atomicAdd(&hist_t[te_dst[i - EU]], 1);
}

// dinv[i] = rsqrt(hist[i] + 1)   (self-loop included)
__global__ void k_dinv(const int* __restrict__ hist, float* __restrict__ dinv, int n) {
    int i = blockIdx.x * blockDim.x + threadIdx.x;
    if (i < n) dinv[i] = rsqrtf((float)hist[i] + 1.0f);
}

// single-block exclusive scan: hist[0..n) -> ptr[0..n]
__global__ __launch_bounds__(1024) void k_scan(const int* __restrict__ hist,
                                               int* __restrict__ ptr, int n) {
    __shared__ int sums[1024];
    int t = threadIdx.x;
    int chunk = (n + 1023) / 1024;
    int lo = t * chunk, hi = min(n, lo + chunk);
    int s = 0;
    for (int i = lo; i < hi; ++i) s += hist[i];
    sums[t] = s;
    __syncthreads();
    for (int off = 1; off < 1024; off <<= 1) {
        int v = (t >= off) ? sums[t - off] : 0;
        __syncthreads();
        sums[t] += v;
        __syncthreads();
    }
    int base = (t == 0) ? 0 : sums[t - 1];
    for (int i = lo; i < hi; ++i) {
        ptr[i] = base;
        base += hist[i];
    }
    if (t == 1023) ptr[n] = base;
}

__global__ void k_copyint(const int* __restrict__ a, int* __restrict__ b, int n) {
    int i = blockIdx.x * blockDim.x + threadIdx.x;
    if (i < n) b[i] = a[i];
}

// place edges into dst-sorted order: esrc[pos] = src[e]
__global__ void k_place(const int* __restrict__ src, const int* __restrict__ dst,
                        int* __restrict__ fill, int* __restrict__ esrc, int E) {
    int e = blockIdx.x * blockDim.x + threadIdx.x;
    if (e >= E) return;
    int d = dst[e];
    int pos = atomicAdd(&fill[d], 1);
    esrc[pos] = src[e];
}

// simple transpose: in [R][K] -> out [K][R]
__global__ void k_transpose(const float* __restrict__ in, float* __restrict__ out,
                            int R, int K) {
    int idx = blockIdx.x * blockDim.x + threadIdx.x;
    if (idx >= R * K) return;
    int j = idx / K, k = idx - j * K;
    out[k * R + j] = in[idx];
}

// ---------------- CSR gather-aggregation (fused self-loop+bias+relu) ----------------
// per wave: one (node, 128-channel chunk); nch = C/128
// out[v,:] = relu( dinv[v]^2*y[v,:] + sum_e dinv[v]*dinv[src]*y[src,:] + b )
__global__ __launch_bounds__(256) void k_gagg(const float* __restrict__ y,
                                              const int* __restrict__ ptr,
                                              const int* __restrict__ esrc,
                                              const float* __restrict__ dinv,
                                              const float* __restrict__ bias,
                                              float* __restrict__ outbuf, int N, int nch) {
    int idx = blockIdx.x * 4 + (threadIdx.x >> 6);
    if (idx >= N * nch) return;
    int v = idx / nch, ch = idx - v * nch;
    int C = nch * 128;
    int lane = threadIdx.x & 63;
    int c0 = ch * 128 + lane;
    float dv = dinv[v];
    const float* yv = y + (size_t)v * C;
    float a0 = dv * dv * yv[c0];
    float a1 = dv * dv * yv[c0 + 64];
    int e = ptr[v], e1 = ptr[v + 1];
    for (; e + 1 < e1; e += 2) {
        int s0 = esrc[e], s1 = esrc[e + 1];
        float cc0 = dv * dinv[s0], cc1 = dv * dinv[s1];
        const float* ys0 = y + (size_t)s0 * C;
        const float* ys1 = y + (size_t)s1 * C;
        a0 += cc0 * ys0[c0];
        a1 += cc0 * ys0[c0 + 64];
        a0 += cc1 * ys1[c0];
        a1 += cc1 * ys1[c0 + 64];
    }
    if (e < e1) {
        int s0 = esrc[e];
        float cc0 = dv * dinv[s0];
        const float* ys0 = y + (size_t)s0 * C;
        a0 += cc0 * ys0[c0];
        a1 += cc0 * ys0[c0 + 64];
    }
    a0 = fmaxf(a0 + bias[c0], 0.f);
    a1 = fmaxf(a1 + bias[c0 + 64], 0.f);
    float* o = outbuf + (size_t)v * C;
    o[c0] = a0;
    o[c0 + 64] = a1;
}

// ---------------- tiled fp32 GEMM: C = A[M,K] @ W[K,N] (+bias)(+relu) ----------------
#define GBM 64
#define GBN 64
#define GBK 16
// flags: bit0 = add bias, bit1 = relu
__global__ __launch_bounds__(256) void k_gemm(const float* __restrict__ A,
                                              const float* __restrict__ W,
                                              const float* __restrict__ bias,
                                              float* __restrict__ C,
                                              int M, int K, int N, int flags) {
    __shared__ float As[GBK][GBM];
    __shared__ float Ws[GBK][GBN];
    int tid = threadIdx.x;
    int bm = blockIdx.x, bn = blockIdx.y;
    int tx = tid & 15, ty = tid >> 4;
    float acc[4][4] = {};

    int arow = tid >> 2;
    int akq  = (tid & 3) * 4;
    int wrow = tid >> 4;
    int wcol = (tid & 15) * 4;

    const float* Aptr = A + (size_t)(bm * GBM + arow) * K + akq;
    const float* Wptr = W + (size_t)wrow * N + (size_t)bn * GBN + wcol;

    for (int k0 = 0; k0 < K; k0 += GBK) {
        float4 av = *(const float4*)(Aptr + k0);
        float4 wv = *(const float4*)(Wptr + (size_t)k0 * N);
        As[akq + 0][arow] = av.x;
        As[akq + 1][arow] = av.y;
        As[akq + 2][arow] = av.z;
        As[akq + 3][arow] = av.w;
        *(float4*)&Ws[wrow][wcol] = wv;
        __syncthreads();
#pragma unroll
        for (int kk = 0; kk < GBK; ++kk) {
            float a0 = As[kk][ty * 4 + 0], a1 = As[kk][ty * 4 + 1];
            float a2 = As[kk][ty * 4 + 2], a3 = As[kk][ty * 4 + 3];
            float w0 = Ws[kk][tx * 4 + 0], w1 = Ws[kk][tx * 4 + 1];
            float w2 = Ws[kk][tx * 4 + 2], w3 = Ws[kk][tx * 4 + 3];
            acc[0][0] += a0 * w0; acc[0][1] += a0 * w1; acc[0][2] += a0 * w2; acc[0][3] += a0 * w3;
            acc[1][0] += a1 * w0; acc[1][1] += a1 * w1; acc[1][2] += a1 * w2; acc[1][3] += a1 * w3;
            acc[2][0] += a2 * w0; acc[2][1] += a2 * w1; acc[2][2] += a2 * w2; acc[2][3] += a2 * w3;
            acc[3][0] += a3 * w0; acc[3][1] += a3 * w1; acc[3][2] += a3 * w2; acc[3][3] += a3 * w3;
        }
        __syncthreads();
    }

#pragma unroll
    for (int i = 0; i < 4; ++i) {
        int row = bm * GBM + ty * 4 + i;
        int col = bn * GBN + tx * 4;
        float4 v = make_float4(acc[i][0], acc[i][1], acc[i][2], acc[i][3]);
        if (flags & 1) {
            v.x += bias[col + 0]; v.y += bias[col + 1];
            v.z += bias[col + 2]; v.w += bias[col + 3];
        }
        if (flags & 2) {
            v.x = fmaxf(v.x, 0.f); v.y = fmaxf(v.y, 0.f);
            v.z = fmaxf(v.z, 0.f); v.w = fmaxf(v.w, 0.f);
        }
        *(float4*)(C + (size_t)row * N + col) = v;
    }
}

// ---------------- tweet attention pooling (S=30, 1024 segs) ----------------
__global__ __launch_bounds__(128) void k_attpool(const float* __restrict__ x,
                                                 const float* __restrict__ gate,
                                                 float* __restrict__ out, int S) {
    const int C = 128;
    int seg = blockIdx.x;
    int c = threadIdx.x;
    size_t base = (size_t)seg * S * C + c;
    float m = -1e30f;
    for (int n = 0; n < S; ++n) m = fmaxf(m, gate[base + (size_t)n * C]);
    float se = 0.f, acc = 0.f;
    for (int n = 0; n < S; ++n) {
        float g = gate[base + (size_t)n * C];
        float e = expf(g - m);
        se += e;
        acc += e * x[base + (size_t)n * C];
    }
    out[(size_t)seg * C + c] = acc / (se + 1e-16f);
}

// ---------------- user attention pooling: chunked 4-stage (S=625, 64 segs) ----------------
__global__ __launch_bounds__(256) void k_pool_pmax(const float* __restrict__ gate,
                                                   float* __restrict__ pmax, int S) {
    int seg = blockIdx.x, ch = blockIdx.y;
    int c = threadIdx.x & 127, j = threadIdx.x >> 7;
    int csz = (S + NCHUNK - 1) / NCHUNK;
    int n0 = ch * csz, n1 = min(S, n0 + csz);
    size_t base = (size_t)seg * S * 128 + c;
    float m = -1e30f;
    for (int n = n0 + j; n < n1; n += 2)
        m = fmaxf(m, gate[base + (size_t)n * 128]);
    __shared__ float red[2][128];
    red[j][c] = m;
    __syncthreads();
    if (j == 0)
        pmax[((size_t)seg * NCHUNK + ch) * 128 + c] = fmaxf(red[0][c], red[1][c]);
}

__global__ __launch_bounds__(128) void k_pool_cmax(const float* __restrict__ pmax,
                                                   float* __restrict__ gmax) {
    int seg = blockIdx.x, c = threadIdx.x;
    float m = -1e30f;
    for (int ch = 0; ch < NCHUNK; ++ch)
        m = fmaxf(m, pmax[((size_t)seg * NCHUNK + ch) * 128 + c]);
    gmax[(size_t)seg * 128 + c] = m;
}

__global__ __launch_bounds__(256) void k_pool_psum(const float* __restrict__ x,
                                                   const float* __restrict__ gate,
                                                   const float* __restrict__ gmax,
                                                   float* __restrict__ pse,
                                                   float* __restrict__ pacc, int S) {
    int seg = blockIdx.x, ch = blockIdx.y;
    int c = threadIdx.x & 127, j = threadIdx.x >> 7;
    int csz = (S + NCHUNK - 1) / NCHUNK;
    int n0 = ch * csz, n1 = min(S, n0 + csz);
    size_t base = (size_t)seg * S * 128 + c;
    float m = gmax[(size_t)seg * 128 + c];
    float se = 0.f, acc = 0.f;
    for (int n = n0 + j; n < n1; n += 2) {
        float g = gate[base + (size_t)n * 128];
        float e = expf(g - m);
        se += e;
        acc += e * x[base + (size_t)n * 128];
    }
    __shared__ float rs[2][128], ra[2][128];
    rs[j][c] = se; ra[j][c] = acc;
    __syncthreads();
    if (j == 0) {
        size_t o = ((size_t)seg * NCHUNK + ch) * 128 + c;
        pse[o]  = rs[0][c] + rs[1][c];
        pacc[o] = ra[0][c] + ra[1][c];
    }
}

__global__ __launch_bounds__(128) void k_pool_final(const float* __restrict__ pse,
                                                    const float* __restrict__ pacc,
                                                    float* __restrict__ out) {
    int seg = blockIdx.x, c = threadIdx.x;
    float se = 0.f, acc = 0.f;
    for (int ch = 0; ch < NCHUNK; ++ch) {
        size_t o = ((size_t)seg * NCHUNK + ch) * 128 + c;
        se += pse[o];
        acc += pacc[o];
    }
    out[(size_t)seg * 128 + c] = acc / (se + 1e-16f);
}

// ---------------- GRU recurrence (gi precomputed): 64 blocks x 768 threads ----------------
// thread t: half = t/384, j = t%384 (gate row). 64 weights/thread in registers.
__global__ __launch_bounds__(768) void k_gru_rec(const float* __restrict__ gi,
                                                 const float* __restrict__ whhT,  // [128][384]
                                                 const float* __restrict__ bhh,
                                                 float* __restrict__ hT) {
    __shared__ float hs[128];
    __shared__ float ph[768];
    int b = blockIdx.x, t = threadIdx.x;
    int half = (t >= 384) ? 1 : 0;
    int j = t - half * 384;
    float w[64];
#pragma unroll
    for (int i = 0; i < 64; ++i)
        w[i] = whhT[(half * 64 + i) * 384 + j];
    float chr = 0.f, chz = 0.f, chn = 0.f;
    if (t < 128) {
        hs[t] = 0.f;
        chr = bhh[t]; chz = bhh[128 + t]; chn = bhh[256 + t];
    }
    __syncthreads();
    for (int step = 0; step < TT; ++step) {
        float a0 = 0.f, a1 = 0.f, a2 = 0.f, a3 = 0.f;
        const float* hbase = hs + half * 64;
#pragma unroll
        for (int i = 0; i < 64; i += 4) {
            float4 hv = *(const float4*)(hbase + i);
            a0 += hv.x * w[i + 0];
            a1 += hv.y * w[i + 1];
            a2 += hv.z * w[i + 2];
            a3 += hv.w * w[i + 3];
        }
        ph[t] = (a0 + a1) + (a2 + a3);
        __syncthreads();
        float hnew = 0.f;
        if (t < 128) {
            const float* girow = gi + ((size_t)b * TT + step) * 384;
            float hr = ph[t] + ph[t + 384] + chr;
            float hz = ph[128 + t] + ph[512 + t] + chz;
            float hn = ph[256 + t] + ph[640 + t] + chn;
            float ir = girow[t], iz = girow[128 + t], in = girow[256 + t];
            float r = 1.f / (1.f + expf(-(ir + hr)));
            float z = 1.f / (1.f + expf(-(iz + hz)));
            float n = tanhf(in + r * hn);
            hnew = (1.f - z) * n + z * hs[t];
        }
        __syncthreads();
        if (t < 128) hs[t] = hnew;
        __syncthreads();
    }
    if (t < 128) hT[(size_t)b * 128 + t] = hs[t];
}

// ---------------- head MLP ----------------
__global__ __launch_bounds__(256) void k_head(const float* __restrict__ uf,
                                              const float* __restrict__ up,
                                              const float* __restrict__ th,
                                              const float* __restrict__ Wd0, const float* __restrict__ bd0,
                                              const float* __restrict__ Wd1, const float* __restrict__ bd1,
                                              const float* __restrict__ Wp, const float* __restrict__ bp,
                                              float* __restrict__ out) {
    __shared__ float in0[288], l1[256], l2[64];
    int b = blockIdx.x, t = threadIdx.x;
    if (t < 32) in0[t] = uf[b * 32 + t];
    else if (t < 160) in0[t] = up[b * 128 + (t - 32)];
    if (t < 128) in0[160 + t] = th[b * 128 + t];
    __syncthreads();
    float acc = bd0[t];
    for (int k = 0; k < 288; ++k) acc += in0[k] * Wd0[k * 256 + t];
    l1[t] = fmaxf(acc, 0.f);
    __syncthreads();
    if (t < 64) {
        float a2 = bd1[t];
        for (int k = 0; k < 256; ++k) a2 += l1[k] * Wd1[k * 64 + t];
        l2[t] = fmaxf(a2, 0.f);
    }
    __syncthreads();
    if (t < 64) {
        float p = l2[t] * Wp[t];
        for (int off = 32; off; off >>= 1) p += __shfl_down(p, off, 64);
        if (t == 0) out[b] = 1.f / (1.f + expf(-(p + bp[0])));
    }
}

// ---------------- launch ----------------
extern "C" void kernel_launch(void* const* d_in, const int* in_sizes, int n_in,
                              void* d_out, int out_size, void* d_ws, size_t ws_size,
                              hipStream_t stream) {
    const float* user_x     = (const float*)d_in[0];
    const float* user_feats = (const float*)d_in[1];
    const float* tweet_x    = (const float*)d_in[2];
    const float* Wu0 = (const float*)d_in[3];  const float* bu0 = (const float*)d_in[4];
    const float* Wu1 = (const float*)d_in[5];  const float* bu1 = (const float*)d_in[6];
    const float* Wgu1 = (const float*)d_in[7]; const float* bgu1 = (const float*)d_in[8];
    const float* Wgu2 = (const float*)d_in[9]; const float* bgu2 = (const float*)d_in[10];
    const float* Wt0 = (const float*)d_in[11]; const float* bt0 = (const float*)d_in[12];
    const float* Wt1 = (const float*)d_in[13]; const float* bt1 = (const float*)d_in[14];
    const float* Wgt1 = (const float*)d_in[15]; const float* bgt1 = (const float*)d_in[16];
    const float* Wgt2 = (const float*)d_in[17]; const float* bgt2 = (const float*)d_in[18];
    const float* W_ih = (const float*)d_in[19]; const float* b_ih = (const float*)d_in[20];
    const float* W_hh = (const float*)d_in[21]; const float* b_hh = (const float*)d_in[22];
    const float* Wd0 = (const float*)d_in[23]; const float* bd0 = (const float*)d_in[24];
    const float* Wd1 = (const float*)d_in[25]; const float* bd1 = (const float*)d_in[26];
    const float* Wp  = (const float*)d_in[27]; const float* bp  = (const float*)d_in[28];
    const int* ue = (const int*)d_in[29];           // [2, EU]
    const int* te = (const int*)d_in[30];           // [2, NTE]
    const int* ue_src = ue, *ue_dst = ue + EU;
    const int* te_src = te, *te_dst = te + NTE;

    float* ws = (float*)d_ws;
    float* region0 = ws;
    const size_t R0 = (size_t)NTNODES * 256 * 2;   // 15,728,640 floats
    float* bufA = region0;
    float* bufB = region0 + (size_t)NU * 128;
    float* bufC = region0 + (size_t)NU * 128 * 2;
    float* tA = region0;
    float* tB = region0 + (size_t)NTNODES * 256;
    size_t o = R0;
    float* dinv_u = ws + o;     o += NU;
    float* dinv_t = ws + o;     o += NTNODES;   // contiguous after dinv_u
    float* user_pool = ws + o;  o += (size_t)BB * 128;
    float* tweet_pool = ws + o; o += (size_t)NSEG_T * 128;
    float* tweet_h = ws + o;    o += (size_t)BB * 128;
    float* wihT = ws + o;       o += 128 * 384;
    float* whhT = ws + o;       o += 128 * 384;
    // int arrays after the float region
    int* iw = (int*)(ws + o);
    int* hist_u = iw;                      // NU  (hist_t contiguous after)
    int* hist_t = iw + NU;                 // NTNODES
    int* ptr_u  = iw + NU + NTNODES;       // NU+1
    int* fill_u = ptr_u + NU + 1;          // NU
    int* esrc_u = fill_u + NU;             // EU
    int* ptr_t  = esrc_u + EU;             // NTNODES+1
    int* fill_t = ptr_t + NTNODES + 1;     // NTNODES
    int* esrc_t = fill_t + NTNODES;        // NTE
    float* out = (float*)d_out;

    // pool partials alias dead bufA region during user att-pool
    float* pmax = bufA;
    float* pse  = bufA + 131072;
    float* pacc = bufA + 262144;
    float* gmax = bufA + 393216;
    // gi [1024,384] aliases region0 after attpool (user+tweet intermediates dead)
    float* gi = region0;

    dim3 b256(256);

    // ---- degrees + CSR (user and tweet) ----
    hipLaunchKernelGGL(k_zeroint, dim3((NU + NTNODES + 255) / 256), b256, 0, stream,
                       hist_u, NU + NTNODES);
    hipLaunchKernelGGL(k_hist2, dim3((EU + NTE + 255) / 256), b256, 0, stream,
                       ue_dst, te_dst, hist_u, hist_t);
    hipLaunchKernelGGL(k_dinv, dim3((NU + NTNODES + 255) / 256), b256, 0, stream,
                       hist_u, dinv_u, NU + NTNODES);
    hipLaunchKernelGGL(k_scan, dim3(1), dim3(1024), 0, stream, hist_u, ptr_u, NU);
    hipLaunchKernelGGL(k_copyint, dim3((NU + 255) / 256), b256, 0, stream, ptr_u, fill_u, NU);
    hipLaunchKernelGGL(k_place, dim3((EU + 255) / 256), b256, 0, stream,
                       ue_src, ue_dst, fill_u, esrc_u, EU);
    hipLaunchKernelGGL(k_scan, dim3(1), dim3(1024), 0, stream, hist_t, ptr_t, NTNODES);
    hipLaunchKernelGGL(k_copyint, dim3((NTNODES + 255) / 256), b256, 0, stream, ptr_t, fill_t, NTNODES);
    hipLaunchKernelGGL(k_place, dim3((NTE + 255) / 256), b256, 0, stream,
                       te_src, te_dst, fill_t, esrc_t, NTE);
    // GRU weight transposes (read-only inputs, no deps)
    hipLaunchKernelGGL(k_transpose, dim3((384 * 128 + 255) / 256), b256, 0, stream,
                       W_ih, wihT, 384, 128);
    hipLaunchKernelGGL(k_transpose, dim3((384 * 128 + 255) / 256), b256, 0, stream,
                       W_hh, whhT, 384, 128);

    const long T128 = (long)NTNODES * 128;
    const float* NB = nullptr;

    // ---- user branch (CSR gather aggregation, fused bias+relu) ----
    hipLaunchKernelGGL(k_gemm, dim3(NU / GBM, 128 / GBN), b256, 0, stream,
                       user_x, Wu0, NB, bufA, NU, 128, 128, 0);
    hipLaunchKernelGGL(k_gagg, dim3((NU + 3) / 4), b256, 0, stream,
                       bufA, ptr_u, esrc_u, dinv_u, bu0, bufB, NU, 1);
    hipLaunchKernelGGL(k_gemm, dim3(NU / GBM, 128 / GBN), b256, 0, stream,
                       bufB, Wu1, NB, bufA, NU, 128, 128, 0);
    hipLaunchKernelGGL(k_gagg, dim3((NU + 3) / 4), b256, 0, stream,
                       bufA, ptr_u, esrc_u, dinv_u, bu1, bufC, NU, 1);
    hipLaunchKernelGGL(k_gemm, dim3(NU / GBM, 128 / GBN), b256, 0, stream,
                       bufC, Wgu1, bgu1, bufA, NU, 128, 128, 1);
    hipLaunchKernelGGL(k_gemm, dim3(NU / GBM, 128 / GBN), b256, 0, stream,
                       bufA, Wgu2, bgu2, bufB, NU, 128, 128, 1);
    hipLaunchKernelGGL(k_pool_pmax, dim3(BB, NCHUNK), b256, 0, stream, bufB, pmax, NU / BB);
    hipLaunchKernelGGL(k_pool_cmax, dim3(BB), dim3(128), 0, stream, pmax, gmax);
    hipLaunchKernelGGL(k_pool_psum, dim3(BB, NCHUNK), b256, 0, stream,
                       bufC, bufB, gmax, pse, pacc, NU / BB);
    hipLaunchKernelGGL(k_pool_final, dim3(BB), dim3(128), 0, stream, pse, pacc, user_pool);

    // ---- tweet branch (CSR gather aggregation) ----
    hipLaunchKernelGGL(k_gemm, dim3(NTNODES / GBM, 256 / GBN), b256, 0, stream,
                       tweet_x, Wt0, NB, tA, NTNODES, 768, 256, 0);
    hipLaunchKernelGGL(k_gagg, dim3((NTNODES * 2 + 3) / 4), b256, 0, stream,
                       tA, ptr_t, esrc_t, dinv_t, bt0, tB, NTNODES, 2);
    hipLaunchKernelGGL(k_gemm, dim3(NTNODES / GBM, 128 / GBN), b256, 0, stream,
                       tB, Wt1, NB, tA, NTNODES, 256, 128, 0);
    float* g2 = tA + T128;      // conv2 output [NT,128]
    hipLaunchKernelGGL(k_gagg, dim3((NTNODES + 3) / 4), b256, 0, stream,
                       tA, ptr_t, esrc_t, dinv_t, bt1, g2, NTNODES, 1);
    hipLaunchKernelGGL(k_gemm, dim3(NTNODES / GBM, 128 / GBN), b256, 0, stream,
                       g2, Wgt1, bgt1, tB, NTNODES, 128, 128, 1);
    hipLaunchKernelGGL(k_gemm, dim3(NTNODES / GBM, 128 / GBN), b256, 0, stream,
                       tB, Wgt2, bgt2, tA, NTNODES, 128, 128, 1);
    hipLaunchKernelGGL(k_attpool, dim3(NSEG_T), dim3(128), 0, stream, g2, tA, tweet_pool, NW);

    // ---- GRU: gi = tweet_pool @ W_ih^T + b_ih  (gi aliases region0, now dead) ----
    hipLaunchKernelGGL(k_gemm, dim3(NSEG_T / GBM, 384 / GBN), b256, 0, stream,
                       tweet_pool, wihT, b_ih, gi, NSEG_T, 128, 384, 1);
    hipLaunchKernelGGL(k_gru_rec, dim3(BB), dim3(768), 0, stream,
                       gi, whhT, b_hh, tweet_h);

    // ---- head ----
    hipLaunchKernelGGL(k_head, dim3(BB), b256, 0, stream,
                       user_feats, user_pool, tweet_h,
                       Wd0, bd0, Wd1, bd1, Wp, bp, out);
}

// Round 5
// 583.123 us; speedup vs baseline: 2.7569x; 1.3088x over previous
//
#include <hip/hip_runtime.h>
#include <hip/hip_bf16.h>

// ---------------- problem constants ----------------
#define NU 40000
#define EU 640000
#define BB 64
#define TT 16
#define NW 30
#define NTNODES 30720       // B*T*NW
#define NTE 61440           // tweet edges
#define NSEG_T 1024         // B*T
#define NCHUNK 16           // chunks per user segment for att-pool

typedef __attribute__((ext_vector_type(8))) short bf16x8;
typedef __attribute__((ext_vector_type(4))) float f32x4;

__device__ __forceinline__ unsigned short f2bf(float x) {
    union { float f; unsigned u; } v; v.f = x;
    unsigned r = v.u + 0x7FFFu + ((v.u >> 16) & 1u);   // RNE
    return (unsigned short)(r >> 16);
}

// ---------------- degree / CSR build kernels ----------------
__global__ void k_zeroint(int* __restrict__ p, int n) {
    int i = blockIdx.x * blockDim.x + threadIdx.x;
    if (i < n) p[i] = 0;
}

__global__ void k_hist2(const int* __restrict__ ue_dst, const int* __restrict__ te_dst,
                        int* __restrict__ hist_u, int* __restrict__ hist_t) {
    int i = blockIdx.x * blockDim.x + threadIdx.x;
    if (i < EU) atomicAdd(&hist_u[ue_dst[i]], 1);
    else if (i < EU + NTE) atomicAdd(&hist_t[te_dst[i - EU]], 1);
}

__global__ void k_dinv(const int* __restrict__ hist, float* __restrict__ dinv, int n) {
    int i = blockIdx.x * blockDim.x + threadIdx.x;
    if (i < n) dinv[i] = rsqrtf((float)hist[i] + 1.0f);
}

__global__ __launch_bounds__(1024) void k_scan(const int* __restrict__ hist,
                                               int* __restrict__ ptr, int n) {
    __shared__ int sums[1024];
    int t = threadIdx.x;
    int chunk = (n + 1023) / 1024;
    int lo = t * chunk, hi = min(n, lo + chunk);
    int s = 0;
    for (int i = lo; i < hi; ++i) s += hist[i];
    sums[t] = s;
    __syncthreads();
    for (int off = 1; off < 1024; off <<= 1) {
        int v = (t >= off) ? sums[t - off] : 0;
        __syncthreads();
        sums[t] += v;
        __syncthreads();
    }
    int base = (t == 0) ? 0 : sums[t - 1];
    for (int i = lo; i < hi; ++i) {
        ptr[i] = base;
        base += hist[i];
    }
    if (t == 1023) ptr[n] = base;
}

__global__ void k_copyint(const int* __restrict__ a, int* __restrict__ b, int n) {
    int i = blockIdx.x * blockDim.x + threadIdx.x;
    if (i < n) b[i] = a[i];
}

__global__ void k_place(const int* __restrict__ src, const int* __restrict__ dst,
                        int* __restrict__ fill, int* __restrict__ esrc, int E) {
    int e = blockIdx.x * blockDim.x + threadIdx.x;
    if (e >= E) return;
    int d = dst[e];
    int pos = atomicAdd(&fill[d], 1);
    esrc[pos] = src[e];
}

// simple transpose: in [R][K] -> out [K][R]  (fp32, for GRU whh only)
__global__ void k_transpose(const float* __restrict__ in, float* __restrict__ out,
                            int R, int K) {
    int idx = blockIdx.x * blockDim.x + threadIdx.x;
    if (idx >= R * K) return;
    int j = idx / K, k = idx - j * K;
    out[k * R + j] = in[idx];
}

// ---------------- weight pre-pack: W[K][N] (or W^T via trans) -> staged bf16 chunks ----
// out halfword f = ((bn*KS+ks)*512 + c)*8 + j  holds  B[k][n], n=bn*128+(c&127),
// k = ks*32 + (c>>7)*8 + j.  (KS = K/32; N % 128 == 0, K % 32 == 0)
__global__ void k_pack(const float* __restrict__ W, unsigned short* __restrict__ out,
                       int K, int N, int trans) {
    int f = blockIdx.x * blockDim.x + threadIdx.x;
    if (f >= K * N) return;
    int j = f & 7;
    int chunk = f >> 3;
    int c = chunk & 511;
    int panel = chunk >> 9;
    int KS = K >> 5;
    int ks = panel % KS;
    int bn = panel / KS;
    int n = bn * 128 + (c & 127);
    int k = ks * 32 + (c >> 7) * 8 + j;
    float v = trans ? W[(size_t)n * K + k] : W[(size_t)k * N + n];
    out[f] = f2bf(v);
}

// ---------------- bf16 MFMA GEMM: C = A[M,K] @ B[K,N] (+bias)(+relu) ----------------
// A fp32 row-major (converted in staging), B pre-packed bf16 (k_pack layout).
// 128x128 tile, BK=32, 4 waves in 2x2 of 64x64, mfma_f32_16x16x32_bf16.
// flags: bit0 = add bias, bit1 = relu.  Requires N%128==0, K%32==0; M guarded.
__global__ __launch_bounds__(256) void k_mgemm(const float* __restrict__ A,
                                               const unsigned short* __restrict__ Bpk,
                                               const float* __restrict__ bias,
                                               float* __restrict__ C,
                                               int M, int K, int N, int flags) {
    __shared__ unsigned short Alds[4096];   // [kblk=4][row=128][kin=8]
    __shared__ unsigned short Blds[4096];   // [kblk=4][col=128][kin=8]
    int tid = threadIdx.x;
    int bm = blockIdx.x, bn = blockIdx.y;
    int lane = tid & 63;
    int w = tid >> 6;
    int wr = (w >> 1) * 64, wc = (w & 1) * 64;
    int l15 = lane & 15, lk = lane >> 4;

    f32x4 acc[4][4];
#pragma unroll
    for (int m = 0; m < 4; ++m)
#pragma unroll
        for (int n = 0; n < 4; ++n) acc[m][n] = (f32x4){0.f, 0.f, 0.f, 0.f};

    int KS = K >> 5;
    const unsigned short* Bpanel = Bpk + (size_t)bn * KS * 4096;

    for (int ks = 0; ks < KS; ++ks) {
        int k0 = ks * 32;
        // stage A (fp32 -> bf16), 4 passes, coalesced float4 reads
#pragma unroll
        for (int p = 0; p < 4; ++p) {
            int f4 = p * 256 + tid;          // 0..1023
            int row = f4 >> 3;               // 0..127
            int kq  = f4 & 7;
            int rg = bm * 128 + row; rg = rg < M ? rg : M - 1;
            float4 av = *(const float4*)(A + (size_t)rg * K + k0 + kq * 4);
            unsigned lo = (unsigned)f2bf(av.x) | ((unsigned)f2bf(av.y) << 16);
            unsigned hi = (unsigned)f2bf(av.z) | ((unsigned)f2bf(av.w) << 16);
            int off = (kq >> 1) * 1024 + row * 8 + (kq & 1) * 4;
            *(uint2*)&Alds[off] = make_uint2(lo, hi);
        }
        // stage B: straight 16B copies (pre-swizzled in global)
        {
            const uint4* bg = (const uint4*)(Bpanel + (size_t)ks * 4096);
            ((uint4*)Blds)[tid] = bg[tid];
            ((uint4*)Blds)[256 + tid] = bg[256 + tid];
        }
        __syncthreads();
        bf16x8 a[4], b[4];
#pragma unroll
        for (int m = 0; m < 4; ++m) {
            int row = wr + m * 16 + l15;
            a[m] = *(const bf16x8*)&Alds[lk * 1024 + row * 8];
        }
#pragma unroll
        for (int n = 0; n < 4; ++n) {
            int col = wc + n * 16 + l15;
            b[n] = *(const bf16x8*)&Blds[lk * 1024 + col * 8];
        }
#pragma unroll
        for (int m = 0; m < 4; ++m)
#pragma unroll
            for (int n = 0; n < 4; ++n)
                acc[m][n] = __builtin_amdgcn_mfma_f32_16x16x32_bf16(a[m], b[n], acc[m][n], 0, 0, 0);
        __syncthreads();
    }

#pragma unroll
    for (int m = 0; m < 4; ++m) {
        int grow0 = bm * 128 + wr + m * 16 + lk * 4;
#pragma unroll
        for (int n = 0; n < 4; ++n) {
            int gcol = bn * 128 + wc + n * 16 + l15;
            float bv = (flags & 1) ? bias[gcol] : 0.f;
#pragma unroll
            for (int i = 0; i < 4; ++i) {
                int grow = grow0 + i;
                if (grow < M) {
                    float v = acc[m][n][i] + bv;
                    if (flags & 2) v = fmaxf(v, 0.f);
                    C[(size_t)grow * N + gcol] = v;
                }
            }
        }
    }
}

// ---------------- CSR gather-aggregation (fused self-loop+bias+relu) ----------------
__global__ __launch_bounds__(256) void k_gagg(const float* __restrict__ y,
                                              const int* __restrict__ ptr,
                                              const int* __restrict__ esrc,
                                              const float* __restrict__ dinv,
                                              const float* __restrict__ bias,
                                              float* __restrict__ outbuf, int N, int nch) {
    int idx = blockIdx.x * 4 + (threadIdx.x >> 6);
    if (idx >= N * nch) return;
    int v = idx / nch, ch = idx - v * nch;
    int C = nch * 128;
    int lane = threadIdx.x & 63;
    int c0 = ch * 128 + lane;
    float dv = dinv[v];
    const float* yv = y + (size_t)v * C;
    float a0 = dv * dv * yv[c0];
    float a1 = dv * dv * yv[c0 + 64];
    int e = ptr[v], e1 = ptr[v + 1];
    for (; e + 1 < e1; e += 2) {
        int s0 = esrc[e], s1 = esrc[e + 1];
        float cc0 = dv * dinv[s0], cc1 = dv * dinv[s1];
        const float* ys0 = y + (size_t)s0 * C;
        const float* ys1 = y + (size_t)s1 * C;
        a0 += cc0 * ys0[c0];
        a1 += cc0 * ys0[c0 + 64];
        a0 += cc1 * ys1[c0];
        a1 += cc1 * ys1[c0 + 64];
    }
    if (e < e1) {
        int s0 = esrc[e];
        float cc0 = dv * dinv[s0];
        const float* ys0 = y + (size_t)s0 * C;
        a0 += cc0 * ys0[c0];
        a1 += cc0 * ys0[c0 + 64];
    }
    a0 = fmaxf(a0 + bias[c0], 0.f);
    a1 = fmaxf(a1 + bias[c0 + 64], 0.f);
    float* o = outbuf + (size_t)v * C;
    o[c0] = a0;
    o[c0 + 64] = a1;
}

// ---------------- tweet attention pooling (S=30, 1024 segs) ----------------
__global__ __launch_bounds__(128) void k_attpool(const float* __restrict__ x,
                                                 const float* __restrict__ gate,
                                                 float* __restrict__ out, int S) {
    const int C = 128;
    int seg = blockIdx.x;
    int c = threadIdx.x;
    size_t base = (size_t)seg * S * C + c;
    float m = -1e30f;
    for (int n = 0; n < S; ++n) m = fmaxf(m, gate[base + (size_t)n * C]);
    float se = 0.f, acc = 0.f;
    for (int n = 0; n < S; ++n) {
        float g = gate[base + (size_t)n * C];
        float e = expf(g - m);
        se += e;
        acc += e * x[base + (size_t)n * C];
    }
    out[(size_t)seg * C + c] = acc / (se + 1e-16f);
}

// ---------------- user attention pooling: chunked 4-stage (S=625, 64 segs) ----------------
__global__ __launch_bounds__(256) void k_pool_pmax(const float* __restrict__ gate,
                                                   float* __restrict__ pmax, int S) {
    int seg = blockIdx.x, ch = blockIdx.y;
    int c = threadIdx.x & 127, j = threadIdx.x >> 7;
    int csz = (S + NCHUNK - 1) / NCHUNK;
    int n0 = ch * csz, n1 = min(S, n0 + csz);
    size_t base = (size_t)seg * S * 128 + c;
    float m = -1e30f;
    for (int n = n0 + j; n < n1; n += 2)
        m = fmaxf(m, gate[base + (size_t)n * 128]);
    __shared__ float red[2][128];
    red[j][c] = m;
    __syncthreads();
    if (j == 0)
        pmax[((size_t)seg * NCHUNK + ch) * 128 + c] = fmaxf(red[0][c], red[1][c]);
}

__global__ __launch_bounds__(128) void k_pool_cmax(const float* __restrict__ pmax,
                                                   float* __restrict__ gmax) {
    int seg = blockIdx.x, c = threadIdx.x;
    float m = -1e30f;
    for (int ch = 0; ch < NCHUNK; ++ch)
        m = fmaxf(m, pmax[((size_t)seg * NCHUNK + ch) * 128 + c]);
    gmax[(size_t)seg * 128 + c] = m;
}

__global__ __launch_bounds__(256) void k_pool_psum(const float* __restrict__ x,
                                                   const float* __restrict__ gate,
                                                   const float* __restrict__ gmax,
                                                   float* __restrict__ pse,
                                                   float* __restrict__ pacc, int S) {
    int seg = blockIdx.x, ch = blockIdx.y;
    int c = threadIdx.x & 127, j = threadIdx.x >> 7;
    int csz = (S + NCHUNK - 1) / NCHUNK;
    int n0 = ch * csz, n1 = min(S, n0 + csz);
    size_t base = (size_t)seg * S * 128 + c;
    float m = gmax[(size_t)seg * 128 + c];
    float se = 0.f, acc = 0.f;
    for (int n = n0 + j; n < n1; n += 2) {
        float g = gate[base + (size_t)n * 128];
        float e = expf(g - m);
        se += e;
        acc += e * x[base + (size_t)n * 128];
    }
    __shared__ float rs[2][128], ra[2][128];
    rs[j][c] = se; ra[j][c] = acc;
    __syncthreads();
    if (j == 0) {
        size_t o = ((size_t)seg * NCHUNK + ch) * 128 + c;
        pse[o]  = rs[0][c] + rs[1][c];
        pacc[o] = ra[0][c] + ra[1][c];
    }
}

__global__ __launch_bounds__(128) void k_pool_final(const float* __restrict__ pse,
                                                    const float* __restrict__ pacc,
                                                    float* __restrict__ out) {
    int seg = blockIdx.x, c = threadIdx.x;
    float se = 0.f, acc = 0.f;
    for (int ch = 0; ch < NCHUNK; ++ch) {
        size_t o = ((size_t)seg * NCHUNK + ch) * 128 + c;
        se += pse[o];
        acc += pacc[o];
    }
    out[(size_t)seg * 128 + c] = acc / (se + 1e-16f);
}

// ---------------- GRU recurrence (gi precomputed): 64 blocks x 768 threads ----------------
__global__ __launch_bounds__(768) void k_gru_rec(const float* __restrict__ gi,
                                                 const float* __restrict__ whhT,  // [128][384]
                                                 const float* __restrict__ bhh,
                                                 float* __restrict__ hT) {
    __shared__ float hs[128];
    __shared__ float ph[768];
    int b = blockIdx.x, t = threadIdx.x;
    int half = (t >= 384) ? 1 : 0;
    int j = t - half * 384;
    float w[64];
#pragma unroll
    for (int i = 0; i < 64; ++i)
        w[i] = whhT[(half * 64 + i) * 384 + j];
    float chr = 0.f, chz = 0.f, chn = 0.f;
    if (t < 128) {
        hs[t] = 0.f;
        chr = bhh[t]; chz = bhh[128 + t]; chn = bhh[256 + t];
    }
    __syncthreads();
    for (int step = 0; step < TT; ++step) {
        float a0 = 0.f, a1 = 0.f, a2 = 0.f, a3 = 0.f;
        const float* hbase = hs + half * 64;
#pragma unroll
        for (int i = 0; i < 64; i += 4) {
            float4 hv = *(const float4*)(hbase + i);
            a0 += hv.x * w[i + 0];
            a1 += hv.y * w[i + 1];
            a2 += hv.z * w[i + 2];
            a3 += hv.w * w[i + 3];
        }
        ph[t] = (a0 + a1) + (a2 + a3);
        __syncthreads();
        float hnew = 0.f;
        if (t < 128) {
            const float* girow = gi + ((size_t)b * TT + step) * 384;
            float hr = ph[t] + ph[t + 384] + chr;
            float hz = ph[128 + t] + ph[512 + t] + chz;
            float hn = ph[256 + t] + ph[640 + t] + chn;
            float ir = girow[t], iz = girow[128 + t], in = girow[256 + t];
            float r = 1.f / (1.f + expf(-(ir + hr)));
            float z = 1.f / (1.f + expf(-(iz + hz)));
            float n = tanhf(in + r * hn);
            hnew = (1.f - z) * n + z * hs[t];
        }
        __syncthreads();
        if (t < 128) hs[t] = hnew;
        __syncthreads();
    }
    if (t < 128) hT[(size_t)b * 128 + t] = hs[t];
}

// ---------------- head MLP ----------------
__global__ __launch_bounds__(256) void k_head(const float* __restrict__ uf,
                                              const float* __restrict__ up,
                                              const float* __restrict__ th,
                                              const float* __restrict__ Wd0, const float* __restrict__ bd0,
                                              const float* __restrict__ Wd1, const float* __restrict__ bd1,
                                              const float* __restrict__ Wp, const float* __restrict__ bp,
                                              float* __restrict__ out) {
    __shared__ float in0[288], l1[256], l2[64];
    int b = blockIdx.x, t = threadIdx.x;
    if (t < 32) in0[t] = uf[b * 32 + t];
    else if (t < 160) in0[t] = up[b * 128 + (t - 32)];
    if (t < 128) in0[160 + t] = th[b * 128 + t];
    __syncthreads();
    float acc = bd0[t];
    for (int k = 0; k < 288; ++k) acc += in0[k] * Wd0[k * 256 + t];
    l1[t] = fmaxf(acc, 0.f);
    __syncthreads();
    if (t < 64) {
        float a2 = bd1[t];
        for (int k = 0; k < 256; ++k) a2 += l1[k] * Wd1[k * 64 + t];
        l2[t] = fmaxf(a2, 0.f);
    }
    __syncthreads();
    if (t < 64) {
        float p = l2[t] * Wp[t];
        for (int off = 32; off; off >>= 1) p += __shfl_down(p, off, 64);
        if (t == 0) out[b] = 1.f / (1.f + expf(-(p + bp[0])));
    }
}

// ---------------- launch ----------------
extern "C" void kernel_launch(void* const* d_in, const int* in_sizes, int n_in,
                              void* d_out, int out_size, void* d_ws, size_t ws_size,
                              hipStream_t stream) {
    const float* user_x     = (const float*)d_in[0];
    const float* user_feats = (const float*)d_in[1];
    const float* tweet_x    = (const float*)d_in[2];
    const float* Wu0 = (const float*)d_in[3];  const float* bu0 = (const float*)d_in[4];
    const float* Wu1 = (const float*)d_in[5];  const float* bu1 = (const float*)d_in[6];
    const float* Wgu1 = (const float*)d_in[7]; const float* bgu1 = (const float*)d_in[8];
    const float* Wgu2 = (const float*)d_in[9]; const float* bgu2 = (const float*)d_in[10];
    const float* Wt0 = (const float*)d_in[11]; const float* bt0 = (const float*)d_in[12];
    const float* Wt1 = (const float*)d_in[13]; const float* bt1 = (const float*)d_in[14];
    const float* Wgt1 = (const float*)d_in[15]; const float* bgt1 = (const float*)d_in[16];
    const float* Wgt2 = (const float*)d_in[17]; const float* bgt2 = (const float*)d_in[18];
    const float* W_ih = (const float*)d_in[19]; const float* b_ih = (const float*)d_in[20];
    const float* W_hh = (const float*)d_in[21]; const float* b_hh = (const float*)d_in[22];
    const float* Wd0 = (const float*)d_in[23]; const float* bd0 = (const float*)d_in[24];
    const float* Wd1 = (const float*)d_in[25]; const float* bd1 = (const float*)d_in[26];
    const float* Wp  = (const float*)d_in[27]; const float* bp  = (const float*)d_in[28];
    const int* ue = (const int*)d_in[29];           // [2, EU]
    const int* te = (const int*)d_in[30];           // [2, NTE]
    const int* ue_src = ue, *ue_dst = ue + EU;
    const int* te_src = te, *te_dst = te + NTE;

    float* ws = (float*)d_ws;
    float* region0 = ws;
    const size_t R0 = (size_t)NTNODES * 256 * 2;   // 15,728,640 floats
    float* bufA = region0;
    float* bufB = region0 + (size_t)NU * 128;
    float* bufC = region0 + (size_t)NU * 128 * 2;
    float* tA = region0;
    float* tB = region0 + (size_t)NTNODES * 256;
    size_t o = R0;
    float* dinv_u = ws + o;     o += NU;
    float* dinv_t = ws + o;     o += NTNODES;   // contiguous after dinv_u
    float* user_pool = ws + o;  o += (size_t)BB * 128;
    float* tweet_pool = ws + o; o += (size_t)NSEG_T * 128;
    float* tweet_h = ws + o;    o += (size_t)BB * 128;
    float* whhT = ws + o;       o += 128 * 384;
    // int arrays
    int* iw = (int*)(ws + o);
    int* hist_u = iw;                      // NU (hist_t contiguous after)
    int* hist_t = iw + NU;                 // NTNODES
    int* ptr_u  = iw + NU + NTNODES;       // NU+1
    int* fill_u = ptr_u + NU + 1;          // NU
    int* esrc_u = fill_u + NU;             // EU
    int* ptr_t  = esrc_u + EU;             // NTNODES+1
    int* fill_t = ptr_t + NTNODES + 1;     // NTNODES
    int* esrc_t = fill_t + NTNODES;        // NTE
    // packed bf16 weights (16B aligned)
    unsigned short* pk = (unsigned short*)(((uintptr_t)(esrc_t + NTE) + 15) & ~(uintptr_t)15);
    unsigned short* pWu0  = pk;               // 128*128
    unsigned short* pWu1  = pWu0  + 16384;
    unsigned short* pWgu1 = pWu1  + 16384;
    unsigned short* pWgu2 = pWgu1 + 16384;
    unsigned short* pWt0  = pWgu2 + 16384;    // 768*256
    unsigned short* pWt1  = pWt0  + 196608;   // 256*128
    unsigned short* pWgt1 = pWt1  + 32768;
    unsigned short* pWgt2 = pWgt1 + 16384;
    unsigned short* pWih  = pWgt2 + 16384;    // 128*384 (from W_ih^T)
    float* out = (float*)d_out;

    // pool partials alias dead bufA region during user att-pool
    float* pmax = bufA;
    float* pse  = bufA + 131072;
    float* pacc = bufA + 262144;
    float* gmax = bufA + 393216;
    // gi [1024,384] aliases region0 after attpool
    float* gi = region0;

    dim3 b256(256);

    // ---- weight packs (inputs only; no deps) ----
    hipLaunchKernelGGL(k_pack, dim3((16384 + 255) / 256), b256, 0, stream, Wu0,  pWu0,  128, 128, 0);
    hipLaunchKernelGGL(k_pack, dim3((16384 + 255) / 256), b256, 0, stream, Wu1,  pWu1,  128, 128, 0);
    hipLaunchKernelGGL(k_pack, dim3((16384 + 255) / 256), b256, 0, stream, Wgu1, pWgu1, 128, 128, 0);
    hipLaunchKernelGGL(k_pack, dim3((16384 + 255) / 256), b256, 0, stream, Wgu2, pWgu2, 128, 128, 0);
    hipLaunchKernelGGL(k_pack, dim3((196608 + 255) / 256), b256, 0, stream, Wt0, pWt0, 768, 256, 0);
    hipLaunchKernelGGL(k_pack, dim3((32768 + 255) / 256), b256, 0, stream, Wt1,  pWt1,  256, 128, 0);
    hipLaunchKernelGGL(k_pack, dim3((16384 + 255) / 256), b256, 0, stream, Wgt1, pWgt1, 128, 128, 0);
    hipLaunchKernelGGL(k_pack, dim3((16384 + 255) / 256), b256, 0, stream, Wgt2, pWgt2, 128, 128, 0);
    hipLaunchKernelGGL(k_pack, dim3((49152 + 255) / 256), b256, 0, stream, W_ih, pWih, 128, 384, 1);
    hipLaunchKernelGGL(k_transpose, dim3((384 * 128 + 255) / 256), b256, 0, stream,
                       W_hh, whhT, 384, 128);

    // ---- degrees + CSR (user and tweet) ----
    hipLaunchKernelGGL(k_zeroint, dim3((NU + NTNODES + 255) / 256), b256, 0, stream,
                       hist_u, NU + NTNODES);
    hipLaunchKernelGGL(k_hist2, dim3((EU + NTE + 255) / 256), b256, 0, stream,
                       ue_dst, te_dst, hist_u, hist_t);
    hipLaunchKernelGGL(k_dinv, dim3((NU + NTNODES + 255) / 256), b256, 0, stream,
                       hist_u, dinv_u, NU + NTNODES);
    hipLaunchKernelGGL(k_scan, dim3(1), dim3(1024), 0, stream, hist_u, ptr_u, NU);
    hipLaunchKernelGGL(k_copyint, dim3((NU + 255) / 256), b256, 0, stream, ptr_u, fill_u, NU);
    hipLaunchKernelGGL(k_place, dim3((EU + 255) / 256), b256, 0, stream,
                       ue_src, ue_dst, fill_u, esrc_u, EU);
    hipLaunchKernelGGL(k_scan, dim3(1), dim3(1024), 0, stream, hist_t, ptr_t, NTNODES);
    hipLaunchKernelGGL(k_copyint, dim3((NTNODES + 255) / 256), b256, 0, stream, ptr_t, fill_t, NTNODES);
    hipLaunchKernelGGL(k_place, dim3((NTE + 255) / 256), b256, 0, stream,
                       te_src, te_dst, fill_t, esrc_t, NTE);

    const long T128 = (long)NTNODES * 128;
    const float* NB = nullptr;
    const int GMU = (NU + 127) / 128;       // 313 (M guarded)

    // ---- user branch ----
    hipLaunchKernelGGL(k_mgemm, dim3(GMU, 1), b256, 0, stream,
                       user_x, pWu0, NB, bufA, NU, 128, 128, 0);
    hipLaunchKernelGGL(k_gagg, dim3((NU + 3) / 4), b256, 0, stream,
                       bufA, ptr_u, esrc_u, dinv_u, bu0, bufB, NU, 1);
    hipLaunchKernelGGL(k_mgemm, dim3(GMU, 1), b256, 0, stream,
                       bufB, pWu1, NB, bufA, NU, 128, 128, 0);
    hipLaunchKernelGGL(k_gagg, dim3((NU + 3) / 4), b256, 0, stream,
                       bufA, ptr_u, esrc_u, dinv_u, bu1, bufC, NU, 1);
    hipLaunchKernelGGL(k_mgemm, dim3(GMU, 1), b256, 0, stream,
                       bufC, pWgu1, bgu1, bufA, NU, 128, 128, 1);
    hipLaunchKernelGGL(k_mgemm, dim3(GMU, 1), b256, 0, stream,
                       bufA, pWgu2, bgu2, bufB, NU, 128, 128, 1);
    hipLaunchKernelGGL(k_pool_pmax, dim3(BB, NCHUNK), b256, 0, stream, bufB, pmax, NU / BB);
    hipLaunchKernelGGL(k_pool_cmax, dim3(BB), dim3(128), 0, stream, pmax, gmax);
    hipLaunchKernelGGL(k_pool_psum, dim3(BB, NCHUNK), b256, 0, stream,
                       bufC, bufB, gmax, pse, pacc, NU / BB);
    hipLaunchKernelGGL(k_pool_final, dim3(BB), dim3(128), 0, stream, pse, pacc, user_pool);

    // ---- tweet branch ----
    hipLaunchKernelGGL(k_mgemm, dim3(NTNODES / 128, 2), b256, 0, stream,
                       tweet_x, pWt0, NB, tA, NTNODES, 768, 256, 0);
    hipLaunchKernelGGL(k_gagg, dim3((NTNODES * 2 + 3) / 4), b256, 0, stream,
                       tA, ptr_t, esrc_t, dinv_t, bt0, tB, NTNODES, 2);
    hipLaunchKernelGGL(k_mgemm, dim3(NTNODES / 128, 1), b256, 0, stream,
                       tB, pWt1, NB, tA, NTNODES, 256, 128, 0);
    float* g2 = tA + T128;      // conv2 output [NT,128]
    hipLaunchKernelGGL(k_gagg, dim3((NTNODES + 3) / 4), b256, 0, stream,
                       tA, ptr_t, esrc_t, dinv_t, bt1, g2, NTNODES, 1);
    hipLaunchKernelGGL(k_mgemm, dim3(NTNODES / 128, 1), b256, 0, stream,
                       g2, pWgt1, bgt1, tB, NTNODES, 128, 128, 1);
    hipLaunchKernelGGL(k_mgemm, dim3(NTNODES / 128, 1), b256, 0, stream,
                       tB, pWgt2, bgt2, tA, NTNODES, 128, 128, 1);
    hipLaunchKernelGGL(k_attpool, dim3(NSEG_T), dim3(128), 0, stream, g2, tA, tweet_pool, NW);

    // ---- GRU: gi = tweet_pool @ W_ih^T + b_ih ----
    hipLaunchKernelGGL(k_mgemm, dim3(NSEG_T / 128, 3), b256, 0, stream,
                       tweet_pool, pWih, b_ih, gi, NSEG_T, 128, 384, 1);
    hipLaunchKernelGGL(k_gru_rec, dim3(BB), dim3(768), 0, stream,
                       gi, whhT, b_hh, tweet_h);

    // ---- head ----
    hipLaunchKernelGGL(k_head, dim3(BB), b256, 0, stream,
                       user_feats, user_pool, tweet_h,
                       Wd0, bd0, Wd1, bd1, Wp, bp, out);
}

// Round 6
// 471.847 us; speedup vs baseline: 3.4071x; 1.2358x over previous
//
#include <hip/hip_runtime.h>
#include <hip/hip_bf16.h>

// ---------------- problem constants ----------------
#define NU 40000
#define EU 640000
#define BB 64
#define TT 16
#define NW 30
#define NTNODES 30720       // B*T*NW
#define NTE 61440           // tweet edges
#define NSEG_T 1024         // B*T
#define NCHUNK 16           // chunks per user segment for att-pool

typedef __attribute__((ext_vector_type(8))) short bf16x8;
typedef __attribute__((ext_vector_type(4))) float f32x4;

__device__ __forceinline__ unsigned short f2bf(float x) {
    union { float f; unsigned u; } v; v.f = x;
    unsigned r = v.u + 0x7FFFu + ((v.u >> 16) & 1u);   // RNE
    return (unsigned short)(r >> 16);
}

// ---------------- degree / CSR build kernels ----------------
__global__ void k_zeroint(int* __restrict__ p, int n) {
    int i = blockIdx.x * blockDim.x + threadIdx.x;
    if (i < n) p[i] = 0;
}

__global__ void k_hist2(const int* __restrict__ ue_dst, const int* __restrict__ te_dst,
                        int* __restrict__ hist_u, int* __restrict__ hist_t) {
    int i = blockIdx.x * blockDim.x + threadIdx.x;
    if (i < EU) atomicAdd(&hist_u[ue_dst[i]], 1);
    else if (i < EU + NTE) atomicAdd(&hist_t[te_dst[i - EU]], 1);
}

__global__ void k_dinv(const int* __restrict__ hist, float* __restrict__ dinv, int n) {
    int i = blockIdx.x * blockDim.x + threadIdx.x;
    if (i < n) dinv[i] = rsqrtf((float)hist[i] + 1.0f);
}

// ---- 3-phase multi-block exclusive scan (1 element/thread) ----
// A: per-block sums
__global__ __launch_bounds__(256) void k_scan_a(const int* __restrict__ hist,
                                                int* __restrict__ bsum, int n) {
    __shared__ int red[256];
    int t = threadIdx.x;
    int i = blockIdx.x * 256 + t;
    red[t] = (i < n) ? hist[i] : 0;
    __syncthreads();
    for (int off = 128; off; off >>= 1) {
        if (t < off) red[t] += red[t + off];
        __syncthreads();
    }
    if (t == 0) bsum[blockIdx.x] = red[0];
}

// B: single block, exclusive scan of nb (<=256) block sums in-place
__global__ __launch_bounds__(256) void k_scan_b(int* __restrict__ bsum, int nb) {
    __shared__ int s[256];
    int t = threadIdx.x;
    s[t] = (t < nb) ? bsum[t] : 0;
    __syncthreads();
    for (int off = 1; off < 256; off <<= 1) {
        int v = (t >= off) ? s[t - off] : 0;
        __syncthreads();
        s[t] += v;
        __syncthreads();
    }
    if (t < nb) bsum[t] = (t == 0) ? 0 : s[t - 1];
}

// C: ptr[i] = bsum[b] + intra-block exclusive prefix; also fill[i] = ptr[i]; ptr[n] at end
__global__ __launch_bounds__(256) void k_scan_c(const int* __restrict__ hist,
                                                const int* __restrict__ bsum,
                                                int* __restrict__ ptr,
                                                int* __restrict__ fill, int n) {
    __shared__ int s[256];
    int t = threadIdx.x;
    int i = blockIdx.x * 256 + t;
    int h = (i < n) ? hist[i] : 0;
    s[t] = h;
    __syncthreads();
    for (int off = 1; off < 256; off <<= 1) {
        int v = (t >= off) ? s[t - off] : 0;
        __syncthreads();
        s[t] += v;
        __syncthreads();
    }
    if (i < n) {
        int excl = bsum[blockIdx.x] + s[t] - h;
        ptr[i] = excl;
        fill[i] = excl;
        if (i == n - 1) ptr[n] = excl + h;
    }
}

__global__ void k_place(const int* __restrict__ src, const int* __restrict__ dst,
                        int* __restrict__ fill, int* __restrict__ esrc, int E) {
    int e = blockIdx.x * blockDim.x + threadIdx.x;
    if (e >= E) return;
    int d = dst[e];
    int pos = atomicAdd(&fill[d], 1);
    esrc[pos] = src[e];
}

// simple transpose: in [R][K] -> out [K][R]  (fp32, for GRU whh only)
__global__ void k_transpose(const float* __restrict__ in, float* __restrict__ out,
                            int R, int K) {
    int idx = blockIdx.x * blockDim.x + threadIdx.x;
    if (idx >= R * K) return;
    int j = idx / K, k = idx - j * K;
    out[k * R + j] = in[idx];
}

// ---------------- weight pre-pack (all 9 weights, one kernel) ----------------
// pack layout: halfword f = ((bn*KS+ks)*512 + c)*8 + j  holds  B[k][n],
// n = bn*128+(c&127), k = ks*32 + (c>>7)*8 + j.  (KS=K/32)
__device__ __forceinline__ void pack_one(const float* __restrict__ W,
                                         unsigned short* __restrict__ out,
                                         int f, int K, int N, int trans) {
    int j = f & 7;
    int chunk = f >> 3;
    int c = chunk & 511;
    int panel = chunk >> 9;
    int KS = K >> 5;
    int ks = panel % KS;
    int bn = panel / KS;
    int n = bn * 128 + (c & 127);
    int k = ks * 32 + (c >> 7) * 8 + j;
    float v = trans ? W[(size_t)n * K + k] : W[(size_t)k * N + n];
    out[f] = f2bf(v);
}

// dst offsets (halfwords): Wu0@0 Wu1@16384 Wgu1@32768 Wgu2@49152 Wt0@65536
// Wt1@262144 Wgt1@294912 Wgt2@311296 Wih@327680; total 376832
__global__ void k_packall(const float* __restrict__ Wu0, const float* __restrict__ Wu1,
                          const float* __restrict__ Wgu1, const float* __restrict__ Wgu2,
                          const float* __restrict__ Wt0, const float* __restrict__ Wt1,
                          const float* __restrict__ Wgt1, const float* __restrict__ Wgt2,
                          const float* __restrict__ Wih,
                          unsigned short* __restrict__ pk) {
    int f = blockIdx.x * blockDim.x + threadIdx.x;
    if (f < 16384)        pack_one(Wu0,  pk + 0,      f,          128, 128, 0);
    else if (f < 32768)   pack_one(Wu1,  pk + 16384,  f - 16384,  128, 128, 0);
    else if (f < 49152)   pack_one(Wgu1, pk + 32768,  f - 32768,  128, 128, 0);
    else if (f < 65536)   pack_one(Wgu2, pk + 49152,  f - 49152,  128, 128, 0);
    else if (f < 262144)  pack_one(Wt0,  pk + 65536,  f - 65536,  768, 256, 0);
    else if (f < 294912)  pack_one(Wt1,  pk + 262144, f - 262144, 256, 128, 0);
    else if (f < 311296)  pack_one(Wgt1, pk + 294912, f - 294912, 128, 128, 0);
    else if (f < 327680)  pack_one(Wgt2, pk + 311296, f - 311296, 128, 128, 0);
    else if (f < 376832)  pack_one(Wih,  pk + 327680, f - 327680, 128, 384, 1);
}

// ---------------- bf16 MFMA GEMM: C = A[M,K] @ B[K,N] (+bias)(+relu) ----------------
__global__ __launch_bounds__(256) void k_mgemm(const float* __restrict__ A,
                                               const unsigned short* __restrict__ Bpk,
                                               const float* __restrict__ bias,
                                               float* __restrict__ C,
                                               int M, int K, int N, int flags) {
    __shared__ unsigned short Alds[4096];   // [kblk=4][row=128][kin=8]
    __shared__ unsigned short Blds[4096];   // [kblk=4][col=128][kin=8]
    int tid = threadIdx.x;
    int bm = blockIdx.x, bn = blockIdx.y;
    int lane = tid & 63;
    int w = tid >> 6;
    int wr = (w >> 1) * 64, wc = (w & 1) * 64;
    int l15 = lane & 15, lk = lane >> 4;

    f32x4 acc[4][4];
#pragma unroll
    for (int m = 0; m < 4; ++m)
#pragma unroll
        for (int n = 0; n < 4; ++n) acc[m][n] = (f32x4){0.f, 0.f, 0.f, 0.f};

    int KS = K >> 5;
    const unsigned short* Bpanel = Bpk + (size_t)bn * KS * 4096;

    for (int ks = 0; ks < KS; ++ks) {
        int k0 = ks * 32;
#pragma unroll
        for (int p = 0; p < 4; ++p) {
            int f4 = p * 256 + tid;
            int row = f4 >> 3;
            int kq  = f4 & 7;
            int rg = bm * 128 + row; rg = rg < M ? rg : M - 1;
            float4 av = *(const float4*)(A + (size_t)rg * K + k0 + kq * 4);
            unsigned lo = (unsigned)f2bf(av.x) | ((unsigned)f2bf(av.y) << 16);
            unsigned hi = (unsigned)f2bf(av.z) | ((unsigned)f2bf(av.w) << 16);
            int off = (kq >> 1) * 1024 + row * 8 + (kq & 1) * 4;
            *(uint2*)&Alds[off] = make_uint2(lo, hi);
        }
        {
            const uint4* bg = (const uint4*)(Bpanel + (size_t)ks * 4096);
            ((uint4*)Blds)[tid] = bg[tid];
            ((uint4*)Blds)[256 + tid] = bg[256 + tid];
        }
        __syncthreads();
        bf16x8 a[4], b[4];
#pragma unroll
        for (int m = 0; m < 4; ++m) {
            int row = wr + m * 16 + l15;
            a[m] = *(const bf16x8*)&Alds[lk * 1024 + row * 8];
        }
#pragma unroll
        for (int n = 0; n < 4; ++n) {
            int col = wc + n * 16 + l15;
            b[n] = *(const bf16x8*)&Blds[lk * 1024 + col * 8];
        }
#pragma unroll
        for (int m = 0; m < 4; ++m)
#pragma unroll
            for (int n = 0; n < 4; ++n)
                acc[m][n] = __builtin_amdgcn_mfma_f32_16x16x32_bf16(a[m], b[n], acc[m][n], 0, 0, 0);
        __syncthreads();
    }

#pragma unroll
    for (int m = 0; m < 4; ++m) {
        int grow0 = bm * 128 + wr + m * 16 + lk * 4;
#pragma unroll
        for (int n = 0; n < 4; ++n) {
            int gcol = bn * 128 + wc + n * 16 + l15;
            float bv = (flags & 1) ? bias[gcol] : 0.f;
#pragma unroll
            for (int i = 0; i < 4; ++i) {
                int grow = grow0 + i;
                if (grow < M) {
                    float v = acc[m][n][i] + bv;
                    if (flags & 2) v = fmaxf(v, 0.f);
                    C[(size_t)grow * N + gcol] = v;
                }
            }
        }
    }
}

// ---------------- CSR gather-aggregation (fused self-loop+bias+relu) ----------------
__global__ __launch_bounds__(256) void k_gagg(const float* __restrict__ y,
                                              const int* __restrict__ ptr,
                                              const int* __restrict__ esrc,
                                              const float* __restrict__ dinv,
                                              const float* __restrict__ bias,
                                              float* __restrict__ outbuf, int N, int nch) {
    int idx = blockIdx.x * 4 + (threadIdx.x >> 6);
    if (idx >= N * nch) return;
    int v = idx / nch, ch = idx - v * nch;
    int C = nch * 128;
    int lane = threadIdx.x & 63;
    int c0 = ch * 128 + lane;
    float dv = dinv[v];
    const float* yv = y + (size_t)v * C;
    float a0 = dv * dv * yv[c0];
    float a1 = dv * dv * yv[c0 + 64];
    int e = ptr[v], e1 = ptr[v + 1];
    for (; e + 1 < e1; e += 2) {
        int s0 = esrc[e], s1 = esrc[e + 1];
        float cc0 = dv * dinv[s0], cc1 = dv * dinv[s1];
        const float* ys0 = y + (size_t)s0 * C;
        const float* ys1 = y + (size_t)s1 * C;
        a0 += cc0 * ys0[c0];
        a1 += cc0 * ys0[c0 + 64];
        a0 += cc1 * ys1[c0];
        a1 += cc1 * ys1[c0 + 64];
    }
    if (e < e1) {
        int s0 = esrc[e];
        float cc0 = dv * dinv[s0];
        const float* ys0 = y + (size_t)s0 * C;
        a0 += cc0 * ys0[c0];
        a1 += cc0 * ys0[c0 + 64];
    }
    a0 = fmaxf(a0 + bias[c0], 0.f);
    a1 = fmaxf(a1 + bias[c0 + 64], 0.f);
    float* o = outbuf + (size_t)v * C;
    o[c0] = a0;
    o[c0 + 64] = a1;
}

// ---------------- tweet attention pooling (S=30, 1024 segs) ----------------
__global__ __launch_bounds__(128) void k_attpool(const float* __restrict__ x,
                                                 const float* __restrict__ gate,
                                                 float* __restrict__ out, int S) {
    const int C = 128;
    int seg = blockIdx.x;
    int c = threadIdx.x;
    size_t base = (size_t)seg * S * C + c;
    float m = -1e30f;
    for (int n = 0; n < S; ++n) m = fmaxf(m, gate[base + (size_t)n * C]);
    float se = 0.f, acc = 0.f;
    for (int n = 0; n < S; ++n) {
        float g = gate[base + (size_t)n * C];
        float e = expf(g - m);
        se += e;
        acc += e * x[base + (size_t)n * C];
    }
    out[(size_t)seg * C + c] = acc / (se + 1e-16f);
}

// ---------------- user attention pooling: chunked 4-stage (S=625, 64 segs) ----------------
__global__ __launch_bounds__(256) void k_pool_pmax(const float* __restrict__ gate,
                                                   float* __restrict__ pmax, int S) {
    int seg = blockIdx.x, ch = blockIdx.y;
    int c = threadIdx.x & 127, j = threadIdx.x >> 7;
    int csz = (S + NCHUNK - 1) / NCHUNK;
    int n0 = ch * csz, n1 = min(S, n0 + csz);
    size_t base = (size_t)seg * S * 128 + c;
    float m = -1e30f;
    for (int n = n0 + j; n < n1; n += 2)
        m = fmaxf(m, gate[base + (size_t)n * 128]);
    __shared__ float red[2][128];
    red[j][c] = m;
    __syncthreads();
    if (j == 0)
        pmax[((size_t)seg * NCHUNK + ch) * 128 + c] = fmaxf(red[0][c], red[1][c]);
}

__global__ __launch_bounds__(128) void k_pool_cmax(const float* __restrict__ pmax,
                                                   float* __restrict__ gmax) {
    int seg = blockIdx.x, c = threadIdx.x;
    float m = -1e30f;
    for (int ch = 0; ch < NCHUNK; ++ch)
        m = fmaxf(m, pmax[((size_t)seg * NCHUNK + ch) * 128 + c]);
    gmax[(size_t)seg * 128 + c] = m;
}

__global__ __launch_bounds__(256) void k_pool_psum(const float* __restrict__ x,
                                                   const float* __restrict__ gate,
                                                   const float* __restrict__ gmax,
                                                   float* __restrict__ pse,
                                                   float* __restrict__ pacc, int S) {
    int seg = blockIdx.x, ch = blockIdx.y;
    int c = threadIdx.x & 127, j = threadIdx.x >> 7;
    int csz = (S + NCHUNK - 1) / NCHUNK;
    int n0 = ch * csz, n1 = min(S, n0 + csz);
    size_t base = (size_t)seg * S * 128 + c;
    float m = gmax[(size_t)seg * 128 + c];
    float se = 0.f, acc = 0.f;
    for (int n = n0 + j; n < n1; n += 2) {
        float g = gate[base + (size_t)n * 128];
        float e = expf(g - m);
        se += e;
        acc += e * x[base + (size_t)n * 128];
    }
    __shared__ float rs[2][128], ra[2][128];
    rs[j][c] = se; ra[j][c] = acc;
    __syncthreads();
    if (j == 0) {
        size_t o = ((size_t)seg * NCHUNK + ch) * 128 + c;
        pse[o]  = rs[0][c] + rs[1][c];
        pacc[o] = ra[0][c] + ra[1][c];
    }
}

__global__ __launch_bounds__(128) void k_pool_final(const float* __restrict__ pse,
                                                    const float* __restrict__ pacc,
                                                    float* __restrict__ out) {
    int seg = blockIdx.x, c = threadIdx.x;
    float se = 0.f, acc = 0.f;
    for (int ch = 0; ch < NCHUNK; ++ch) {
        size_t o = ((size_t)seg * NCHUNK + ch) * 128 + c;
        se += pse[o];
        acc += pacc[o];
    }
    out[(size_t)seg * 128 + c] = acc / (se + 1e-16f);
}

// ---------------- GRU recurrence (gi precomputed): 64 blocks x 768 threads ----------------
__global__ __launch_bounds__(768) void k_gru_rec(const float* __restrict__ gi,
                                                 const float* __restrict__ whhT,  // [128][384]
                                                 const float* __restrict__ bhh,
                                                 float* __restrict__ hT) {
    __shared__ float hs[128];
    __shared__ float ph[768];
    int b = blockIdx.x, t = threadIdx.x;
    int half = (t >= 384) ? 1 : 0;
    int j = t - half * 384;
    float w[64];
#pragma unroll
    for (int i = 0; i < 64; ++i)
        w[i] = whhT[(half * 64 + i) * 384 + j];
    float chr = 0.f, chz = 0.f, chn = 0.f;
    if (t < 128) {
        hs[t] = 0.f;
        chr = bhh[t]; chz = bhh[128 + t]; chn = bhh[256 + t];
    }
    __syncthreads();
    for (int step = 0; step < TT; ++step) {
        float a0 = 0.f, a1 = 0.f, a2 = 0.f, a3 = 0.f;
        const float* hbase = hs + half * 64;
#pragma unroll
        for (int i = 0; i < 64; i += 4) {
            float4 hv = *(const float4*)(hbase + i);
            a0 += hv.x * w[i + 0];
            a1 += hv.y * w[i + 1];
            a2 += hv.z * w[i + 2];
            a3 += hv.w * w[i + 3];
        }
        ph[t] = (a0 + a1) + (a2 + a3);
        __syncthreads();
        float hnew = 0.f;
        if (t < 128) {
            const float* girow = gi + ((size_t)b * TT + step) * 384;
            float hr = ph[t] + ph[t + 384] + chr;
            float hz = ph[128 + t] + ph[512 + t] + chz;
            float hn = ph[256 + t] + ph[640 + t] + chn;
            float ir = girow[t], iz = girow[128 + t], in = girow[256 + t];
            float r = 1.f / (1.f + expf(-(ir + hr)));
            float z = 1.f / (1.f + expf(-(iz + hz)));
            float n = tanhf(in + r * hn);
            hnew = (1.f - z) * n + z * hs[t];
        }
        __syncthreads();
        if (t < 128) hs[t] = hnew;
        __syncthreads();
    }
    if (t < 128) hT[(size_t)b * 128 + t] = hs[t];
}

// ---------------- head MLP ----------------
__global__ __launch_bounds__(256) void k_head(const float* __restrict__ uf,
                                              const float* __restrict__ up,
                                              const float* __restrict__ th,
                                              const float* __restrict__ Wd0, const float* __restrict__ bd0,
                                              const float* __restrict__ Wd1, const float* __restrict__ bd1,
                                              const float* __restrict__ Wp, const float* __restrict__ bp,
                                              float* __restrict__ out) {
    __shared__ float in0[288], l1[256], l2[64];
    int b = blockIdx.x, t = threadIdx.x;
    if (t < 32) in0[t] = uf[b * 32 + t];
    else if (t < 160) in0[t] = up[b * 128 + (t - 32)];
    if (t < 128) in0[160 + t] = th[b * 128 + t];
    __syncthreads();
    float acc = bd0[t];
    for (int k = 0; k < 288; ++k) acc += in0[k] * Wd0[k * 256 + t];
    l1[t] = fmaxf(acc, 0.f);
    __syncthreads();
    if (t < 64) {
        float a2 = bd1[t];
        for (int k = 0; k < 256; ++k) a2 += l1[k] * Wd1[k * 64 + t];
        l2[t] = fmaxf(a2, 0.f);
    }
    __syncthreads();
    if (t < 64) {
        float p = l2[t] * Wp[t];
        for (int off = 32; off; off >>= 1) p += __shfl_down(p, off, 64);
        if (t == 0) out[b] = 1.f / (1.f + expf(-(p + bp[0])));
    }
}

// ---------------- launch ----------------
extern "C" void kernel_launch(void* const* d_in, const int* in_sizes, int n_in,
                              void* d_out, int out_size, void* d_ws, size_t ws_size,
                              hipStream_t stream) {
    const float* user_x     = (const float*)d_in[0];
    const float* user_feats = (const float*)d_in[1];
    const float* tweet_x    = (const float*)d_in[2];
    const float* Wu0 = (const float*)d_in[3];  const float* bu0 = (const float*)d_in[4];
    const float* Wu1 = (const float*)d_in[5];  const float* bu1 = (const float*)d_in[6];
    const float* Wgu1 = (const float*)d_in[7]; const float* bgu1 = (const float*)d_in[8];
    const float* Wgu2 = (const float*)d_in[9]; const float* bgu2 = (const float*)d_in[10];
    const float* Wt0 = (const float*)d_in[11]; const float* bt0 = (const float*)d_in[12];
    const float* Wt1 = (const float*)d_in[13]; const float* bt1 = (const float*)d_in[14];
    const float* Wgt1 = (const float*)d_in[15]; const float* bgt1 = (const float*)d_in[16];
    const float* Wgt2 = (const float*)d_in[17]; const float* bgt2 = (const float*)d_in[18];
    const float* W_ih = (const float*)d_in[19]; const float* b_ih = (const float*)d_in[20];
    const float* W_hh = (const float*)d_in[21]; const float* b_hh = (const float*)d_in[22];
    const float* Wd0 = (const float*)d_in[23]; const float* bd0 = (const float*)d_in[24];
    const float* Wd1 = (const float*)d_in[25]; const float* bd1 = (const float*)d_in[26];
    const float* Wp  = (const float*)d_in[27]; const float* bp  = (const float*)d_in[28];
    const int* ue = (const int*)d_in[29];           // [2, EU]
    const int* te = (const int*)d_in[30];           // [2, NTE]
    const int* ue_src = ue, *ue_dst = ue + EU;
    const int* te_src = te, *te_dst = te + NTE;

    float* ws = (float*)d_ws;
    float* region0 = ws;
    const size_t R0 = (size_t)NTNODES * 256 * 2;   // 15,728,640 floats
    float* bufA = region0;
    float* bufB = region0 + (size_t)NU * 128;
    float* bufC = region0 + (size_t)NU * 128 * 2;
    float* tA = region0;
    float* tB = region0 + (size_t)NTNODES * 256;
    size_t o = R0;
    float* dinv_u = ws + o;     o += NU;
    float* dinv_t = ws + o;     o += NTNODES;   // contiguous after dinv_u
    float* user_pool = ws + o;  o += (size_t)BB * 128;
    float* tweet_pool = ws + o; o += (size_t)NSEG_T * 128;
    float* tweet_h = ws + o;    o += (size_t)BB * 128;
    float* whhT = ws + o;       o += 128 * 384;
    // int arrays
    int* iw = (int*)(ws + o);
    int* hist_u = iw;                      // NU (hist_t contiguous after)
    int* hist_t = iw + NU;                 // NTNODES
    int* ptr_u  = iw + NU + NTNODES;       // NU+1
    int* fill_u = ptr_u + NU + 1;          // NU
    int* esrc_u = fill_u + NU;             // EU
    int* ptr_t  = esrc_u + EU;             // NTNODES+1
    int* fill_t = ptr_t + NTNODES + 1;     // NTNODES
    int* esrc_t = fill_t + NTNODES;        // NTE
    int* bsum_u = esrc_t + NTE;            // 256
    int* bsum_t = bsum_u + 256;            // 256
    // packed bf16 weights (16B aligned)
    unsigned short* pk = (unsigned short*)(((uintptr_t)(bsum_t + 256) + 15) & ~(uintptr_t)15);
    unsigned short* pWu0  = pk;               // offsets match k_packall
    unsigned short* pWu1  = pWu0  + 16384;
    unsigned short* pWgu1 = pWu1  + 16384;
    unsigned short* pWgu2 = pWgu1 + 16384;
    unsigned short* pWt0  = pWgu2 + 16384;
    unsigned short* pWt1  = pWt0  + 196608;
    unsigned short* pWgt1 = pWt1  + 32768;
    unsigned short* pWgt2 = pWgt1 + 16384;
    unsigned short* pWih  = pWgt2 + 16384;
    float* out = (float*)d_out;

    // pool partials alias dead bufA region during user att-pool
    float* pmax = bufA;
    float* pse  = bufA + 131072;
    float* pacc = bufA + 262144;
    float* gmax = bufA + 393216;
    // gi [1024,384] aliases region0 after attpool
    float* gi = region0;

    dim3 b256(256);
    const int NBU = (NU + 255) / 256;        // 157
    const int NBT = (NTNODES + 255) / 256;   // 120

    // ---- weight packs (single fused kernel) + GRU whh transpose ----
    hipLaunchKernelGGL(k_packall, dim3((376832 + 255) / 256), b256, 0, stream,
                       Wu0, Wu1, Wgu1, Wgu2, Wt0, Wt1, Wgt1, Wgt2, W_ih, pk);
    hipLaunchKernelGGL(k_transpose, dim3((384 * 128 + 255) / 256), b256, 0, stream,
                       W_hh, whhT, 384, 128);

    // ---- degrees + CSR (user and tweet) ----
    hipLaunchKernelGGL(k_zeroint, dim3((NU + NTNODES + 255) / 256), b256, 0, stream,
                       hist_u, NU + NTNODES);
    hipLaunchKernelGGL(k_hist2, dim3((EU + NTE + 255) / 256), b256, 0, stream,
                       ue_dst, te_dst, hist_u, hist_t);
    hipLaunchKernelGGL(k_dinv, dim3((NU + NTNODES + 255) / 256), b256, 0, stream,
                       hist_u, dinv_u, NU + NTNODES);
    hipLaunchKernelGGL(k_scan_a, dim3(NBU), b256, 0, stream, hist_u, bsum_u, NU);
    hipLaunchKernelGGL(k_scan_b, dim3(1), b256, 0, stream, bsum_u, NBU);
    hipLaunchKernelGGL(k_scan_c, dim3(NBU), b256, 0, stream, hist_u, bsum_u, ptr_u, fill_u, NU);
    hipLaunchKernelGGL(k_place, dim3((EU + 255) / 256), b256, 0, stream,
                       ue_src, ue_dst, fill_u, esrc_u, EU);
    hipLaunchKernelGGL(k_scan_a, dim3(NBT), b256, 0, stream, hist_t, bsum_t, NTNODES);
    hipLaunchKernelGGL(k_scan_b, dim3(1), b256, 0, stream, bsum_t, NBT);
    hipLaunchKernelGGL(k_scan_c, dim3(NBT), b256, 0, stream, hist_t, bsum_t, ptr_t, fill_t, NTNODES);
    hipLaunchKernelGGL(k_place, dim3((NTE + 255) / 256), b256, 0, stream,
                       te_src, te_dst, fill_t, esrc_t, NTE);

    const long T128 = (long)NTNODES * 128;
    const float* NB = nullptr;
    const int GMU = (NU + 127) / 128;       // 313 (M guarded)

    // ---- user branch ----
    hipLaunchKernelGGL(k_mgemm, dim3(GMU, 1), b256, 0, stream,
                       user_x, pWu0, NB, bufA, NU, 128, 128, 0);
    hipLaunchKernelGGL(k_gagg, dim3((NU + 3) / 4), b256, 0, stream,
                       bufA, ptr_u, esrc_u, dinv_u, bu0, bufB, NU, 1);
    hipLaunchKernelGGL(k_mgemm, dim3(GMU, 1), b256, 0, stream,
                       bufB, pWu1, NB, bufA, NU, 128, 128, 0);
    hipLaunchKernelGGL(k_gagg, dim3((NU + 3) / 4), b256, 0, stream,
                       bufA, ptr_u, esrc_u, dinv_u, bu1, bufC, NU, 1);
    hipLaunchKernelGGL(k_mgemm, dim3(GMU, 1), b256, 0, stream,
                       bufC, pWgu1, bgu1, bufA, NU, 128, 128, 1);
    hipLaunchKernelGGL(k_mgemm, dim3(GMU, 1), b256, 0, stream,
                       bufA, pWgu2, bgu2, bufB, NU, 128, 128, 1);
    hipLaunchKernelGGL(k_pool_pmax, dim3(BB, NCHUNK), b256, 0, stream, bufB, pmax, NU / BB);
    hipLaunchKernelGGL(k_pool_cmax, dim3(BB), dim3(128), 0, stream, pmax, gmax);
    hipLaunchKernelGGL(k_pool_psum, dim3(BB, NCHUNK), b256, 0, stream,
                       bufC, bufB, gmax, pse, pacc, NU / BB);
    hipLaunchKernelGGL(k_pool_final, dim3(BB), dim3(128), 0, stream, pse, pacc, user_pool);

    // ---- tweet branch ----
    hipLaunchKernelGGL(k_mgemm, dim3(NTNODES / 128, 2), b256, 0, stream,
                       tweet_x, pWt0, NB, tA, NTNODES, 768, 256, 0);
    hipLaunchKernelGGL(k_gagg, dim3((NTNODES * 2 + 3) / 4), b256, 0, stream,
                       tA, ptr_t, esrc_t, dinv_t, bt0, tB, NTNODES, 2);
    hipLaunchKernelGGL(k_mgemm, dim3(NTNODES / 128, 1), b256, 0, stream,
                       tB, pWt1, NB, tA, NTNODES, 256, 128, 0);
    float* g2 = tA + T128;      // conv2 output [NT,128]
    hipLaunchKernelGGL(k_gagg, dim3((NTNODES + 3) / 4), b256, 0, stream,
                       tA, ptr_t, esrc_t, dinv_t, bt1, g2, NTNODES, 1);
    hipLaunchKernelGGL(k_mgemm, dim3(NTNODES / 128, 1), b256, 0, stream,
                       g2, pWgt1, bgt1, tB, NTNODES, 128, 128, 1);
    hipLaunchKernelGGL(k_mgemm, dim3(NTNODES / 128, 1), b256, 0, stream,
                       tB, pWgt2, bgt2, tA, NTNODES, 128, 128, 1);
    hipLaunchKernelGGL(k_attpool, dim3(NSEG_T), dim3(128), 0, stream, g2, tA, tweet_pool, NW);

    // ---- GRU: gi = tweet_pool @ W_ih^T + b_ih ----
    hipLaunchKernelGGL(k_mgemm, dim3(NSEG_T / 128, 3), b256, 0, stream,
                       tweet_pool, pWih, b_ih, gi, NSEG_T, 128, 384, 1);
    hipLaunchKernelGGL(k_gru_rec, dim3(BB), dim3(768), 0, stream,
                       gi, whhT, b_hh, tweet_h);

    // ---- head ----
    hipLaunchKernelGGL(k_head, dim3(BB), b256, 0, stream,
                       user_feats, user_pool, tweet_h,
                       Wd0, bd0, Wd1, bd1, Wp, bp, out);
}